// Round 9
// baseline (1069.308 us; speedup 1.0000x reference)
//
#include <hip/hip_runtime.h>

// GCN sparse conv: out = relu( sparse(adj) @ ( sparse(x) @ W ) )
// COO->CSR via exact two-pass radix sort:
//   hist (100K row counters) -> hierarchical scan -> offsets/cursors
//   pass A: single sequential read of (rows,cols,vals); LDS chunk-aggregated
//           append of {row, packed_edge} into EXACTLY-sized partition queues
//           (partition = row>>14; queue segment p = [off[p<<14], off[(p+1)<<14]))
//   pass B: blocks (blockIdx&7 == p -> XCD p) stream queue p sequentially and
//           scatter edge words via pos[] cursors into an L2-resident window.
// Queue buffer shared between matrices (x sort, then adj sort, serialized).
// SpMM: one 64-lane wave per row, register accumulation, no atomics.
// Edges packed 4B: x = col(16b)<<16 | bf16(val); adj = col(17b)<<15 | bf15(val>=0).
// W converted to bf16 once (halves spmm1 gather); xw stored bf16.

constexpr int OUT_DIM = 256;
constexpr int PSH     = 14;     // partition shift: 16384 rows per partition
constexpr int NPART   = 8;      // max partitions (= XCDs)

typedef float        f32x4 __attribute__((ext_vector_type(4)));
typedef unsigned int u32x2 __attribute__((ext_vector_type(2)));

static __device__ __forceinline__ unsigned f2bf(float f) {
    unsigned u = __float_as_uint(f);
    return (u + 0x7FFFu + ((u >> 16) & 1u)) >> 16;   // round-nearest-even
}

// ---------------- histogram (both matrices, one pass) ----------------

__global__ void hist2(const int* __restrict__ xr, int nx, int* __restrict__ cx,
                      const int* __restrict__ ar, int na, int* __restrict__ ca) {
    int i = blockIdx.x * blockDim.x + threadIdx.x;
    const int stride = gridDim.x * blockDim.x;
    const int tot = nx + na;
    for (; i < tot; i += stride) {
        if (i < nx) atomicAdd(&cx[__builtin_nontemporal_load(&xr[i])], 1);
        else        atomicAdd(&ca[__builtin_nontemporal_load(&ar[i - nx])], 1);
    }
}

// ---------------- hierarchical scan (merged x+adj) ----------------

__global__ void block_sums2(const int* __restrict__ cx, const int* __restrict__ ca,
                            int n, int nb, int* __restrict__ bx, int* __restrict__ ba) {
    __shared__ int sh[256];
    int b = (int)blockIdx.x;
    const int* counts; int* bs;
    if (b < nb) { counts = cx; bs = bx; } else { counts = ca; bs = ba; b -= nb; }
    const int t = threadIdx.x;
    const int idx = b * 1024 + t * 4;
    int s = 0;
    if (idx + 3 < n) {
        int4 v = *reinterpret_cast<const int4*>(counts + idx);
        s = v.x + v.y + v.z + v.w;
    } else {
        for (int k = 0; k < 4; ++k) if (idx + k < n) s += counts[idx + k];
    }
    sh[t] = s;
    __syncthreads();
    for (int off = 128; off > 0; off >>= 1) {
        if (t < off) sh[t] += sh[t + off];
        __syncthreads();
    }
    if (t == 0) bs[b] = sh[0];
}

__global__ void scan_bsums2(int* __restrict__ bx, int* __restrict__ ba, int nb) {
    __shared__ int sh[1024];
    int* bs = (blockIdx.x == 0) ? bx : ba;
    const int t = threadIdx.x;
    const int v = (t < nb) ? bs[t] : 0;
    sh[t] = v;
    __syncthreads();
    for (int off = 1; off < 1024; off <<= 1) {
        int cur = sh[t];
        int a = (t >= off) ? sh[t - off] : 0;
        __syncthreads();
        sh[t] = cur + a;
        __syncthreads();
    }
    if (t < nb) bs[t] = sh[t] - v;   // exclusive
}

__global__ void scan_finalize2(int* __restrict__ px, const int* __restrict__ bx,
                               int* __restrict__ ox, int nnzx,
                               int* __restrict__ pa, const int* __restrict__ ba,
                               int* __restrict__ oa, int nnza,
                               int n, int nb) {
    __shared__ int sh[256];
    int b = (int)blockIdx.x;
    int* pos; const int* boff; int* offsets; int nnz;
    if (b < nb) { pos = px; boff = bx; offsets = ox; nnz = nnzx; }
    else        { pos = pa; boff = ba; offsets = oa; nnz = nnza; b -= nb; }
    const int t = threadIdx.x;
    const int idx = b * 1024 + t * 4;
    int c0 = 0, c1 = 0, c2 = 0, c3 = 0;
    if (idx + 3 < n) {
        int4 v = *reinterpret_cast<const int4*>(pos + idx);
        c0 = v.x; c1 = v.y; c2 = v.z; c3 = v.w;
    } else {
        if (idx + 0 < n) c0 = pos[idx + 0];
        if (idx + 1 < n) c1 = pos[idx + 1];
        if (idx + 2 < n) c2 = pos[idx + 2];
        if (idx + 3 < n) c3 = pos[idx + 3];
    }
    const int tsum = c0 + c1 + c2 + c3;
    sh[t] = tsum;
    __syncthreads();
    for (int off = 1; off < 256; off <<= 1) {
        int cur = sh[t];
        int a = (t >= off) ? sh[t - off] : 0;
        __syncthreads();
        sh[t] = cur + a;
        __syncthreads();
    }
    const int base = boff[b] + sh[t] - tsum;
    const int o0 = base, o1 = o0 + c0, o2 = o1 + c1, o3 = o2 + c2;
    if (idx + 3 < n) {
        *reinterpret_cast<int4*>(offsets + idx) = make_int4(o0, o1, o2, o3);
        *reinterpret_cast<int4*>(pos + idx)     = make_int4(o0, o1, o2, o3);
    } else {
        if (idx + 0 < n) { offsets[idx + 0] = o0; pos[idx + 0] = o0; }
        if (idx + 1 < n) { offsets[idx + 1] = o1; pos[idx + 1] = o1; }
        if (idx + 2 < n) { offsets[idx + 2] = o2; pos[idx + 2] = o2; }
        if (idx + 3 < n) { offsets[idx + 3] = o3; pos[idx + 3] = o3; }
    }
    if (b == 0 && t == 0) offsets[n] = nnz;
}

// ---------------- prep: W -> bf16 (u32x2 per 4 cols) + queue-cursor init ------

__global__ void prep(const float* __restrict__ W, u32x2* __restrict__ Wb, int n_wb,
                     const int* __restrict__ off_x, int* __restrict__ qcur_x,
                     const int* __restrict__ off_a, int* __restrict__ qcur_a, int N) {
    const int i = (int)(blockIdx.x * blockDim.x + threadIdx.x);
    if (i < n_wb) {
        const float4 w = reinterpret_cast<const float4*>(W)[i];
        u32x2 o;
        o.x = f2bf(w.x) | (f2bf(w.y) << 16);
        o.y = f2bf(w.z) | (f2bf(w.w) << 16);
        Wb[i] = o;
    }
    if (blockIdx.x == 0 && threadIdx.x < 2 * NPART) {
        const int p = (int)threadIdx.x & (NPART - 1);
        const int r = min(p << PSH, N);
        if (threadIdx.x < NPART) qcur_x[p] = off_x[r];
        else                     qcur_a[p] = off_a[r];
    }
}

// ---------------- pass A: sequential read -> exact partition queues ----------
// One 1024-edge chunk per block. LDS aggregation: count per partition, one
// global fetch-add per partition, LDS re-rank, coalesced contiguous writes.
template <bool ADJ>
__global__ void passA(const int* __restrict__ rows, const int* __restrict__ cols,
                      const float* __restrict__ vals, int* __restrict__ qcur,
                      u32x2* __restrict__ q, int nnz) {
    __shared__ u32x2 stage[1024];
    __shared__ int lcnt[NPART], lbase[NPART], lstart[NPART];
    const int t    = (int)threadIdx.x;
    const int base = (int)blockIdx.x * 1024;
    const int cnt  = min(1024, nnz - base);

    if (t < NPART) lcnt[t] = 0;
    __syncthreads();

    u32x2 ent[4];
    int   my[4];
    bool  ok[4];
    #pragma unroll
    for (int k = 0; k < 4; ++k) {
        const int i = base + k * 256 + t;
        ok[k] = (i < nnz);
        if (ok[k]) {
            const int r = __builtin_nontemporal_load(&rows[i]);
            const int c = __builtin_nontemporal_load(&cols[i]);
            const float v = __builtin_nontemporal_load(&vals[i]);
            const unsigned p = (unsigned)r >> PSH;
            unsigned e;
            if (ADJ) e = ((unsigned)c << 15) | (f2bf(v) & 0x7FFFu);
            else     e = ((unsigned)c << 16) | f2bf(v);
            ent[k].x = (p << 28) | (unsigned)r;
            ent[k].y = e;
            my[k]  = atomicAdd(&lcnt[p], 1);
        }
    }
    __syncthreads();
    if (t == 0) {
        int s = 0;
        #pragma unroll
        for (int j = 0; j < NPART; ++j) { lstart[j] = s; s += lcnt[j]; }
    }
    __syncthreads();
    if (t < NPART) lbase[t] = atomicAdd(&qcur[t], lcnt[t]);
    __syncthreads();
    #pragma unroll
    for (int k = 0; k < 4; ++k)
        if (ok[k]) stage[lstart[ent[k].x >> 28] + my[k]] = ent[k];
    __syncthreads();
    for (int s = t; s < cnt; s += 256) {
        const u32x2 e = stage[s];
        const int   p = (int)(e.x >> 28);
        q[lbase[p] + (s - lstart[p])] = e;
    }
}

// ---------------- pass B: stream queue p, scatter into L2-resident window ----

__global__ void passB(const u32x2* __restrict__ q, const int* __restrict__ offsets,
                      int* __restrict__ pos, unsigned* __restrict__ edges, int N) {
    const int p     = (int)(blockIdx.x & (NPART - 1));
    const int lb    = (int)(blockIdx.x >> 3);
    const int nloc  = (int)(gridDim.x >> 3);
    const int start = offsets[min(p << PSH, N)];
    const int end   = offsets[min((p + 1) << PSH, N)];
    for (int i = start + lb * 256 + (int)threadIdx.x; i < end; i += nloc * 256) {
        const u32x2 e = __builtin_nontemporal_load(&q[i]);
        const int   r = (int)(e.x & 0x0FFFFFFFu);
        const int   s = atomicAdd(&pos[r], 1);
        edges[s] = e.y;
    }
}

// ---------------- SpMM1: xw(bf16) = sparse(x) @ Wb(bf16) ----------------

__global__ void spmm1(const int* __restrict__ offsets, const unsigned* __restrict__ edges,
                      const u32x2* __restrict__ Wb, u32x2* __restrict__ xw, int n) {
    const int wave = (int)((blockIdx.x * blockDim.x + threadIdx.x) >> 6);
    const int lane = (int)(threadIdx.x & 63);
    if (wave >= n) return;
    const int s = offsets[wave], e = offsets[wave + 1];

    float4 acc = make_float4(0.f, 0.f, 0.f, 0.f);
    int i = s;
    for (; i + 1 < e; i += 2) {
        const unsigned p0 = __builtin_nontemporal_load(&edges[i]);
        const unsigned p1 = __builtin_nontemporal_load(&edges[i + 1]);
        const u32x2 g0 = Wb[(size_t)(p0 >> 16) * 64 + lane];
        const u32x2 g1 = Wb[(size_t)(p1 >> 16) * 64 + lane];
        const float v0 = __uint_as_float(p0 << 16);
        const float v1 = __uint_as_float(p1 << 16);
        acc.x += v0 * __uint_as_float(g0.x << 16)          + v1 * __uint_as_float(g1.x << 16);
        acc.y += v0 * __uint_as_float(g0.x & 0xFFFF0000u)  + v1 * __uint_as_float(g1.x & 0xFFFF0000u);
        acc.z += v0 * __uint_as_float(g0.y << 16)          + v1 * __uint_as_float(g1.y << 16);
        acc.w += v0 * __uint_as_float(g0.y & 0xFFFF0000u)  + v1 * __uint_as_float(g1.y & 0xFFFF0000u);
    }
    if (i < e) {
        const unsigned p0 = __builtin_nontemporal_load(&edges[i]);
        const u32x2 g0 = Wb[(size_t)(p0 >> 16) * 64 + lane];
        const float v0 = __uint_as_float(p0 << 16);
        acc.x += v0 * __uint_as_float(g0.x << 16);
        acc.y += v0 * __uint_as_float(g0.x & 0xFFFF0000u);
        acc.z += v0 * __uint_as_float(g0.y << 16);
        acc.w += v0 * __uint_as_float(g0.y & 0xFFFF0000u);
    }
    u32x2 o;
    o.x = f2bf(acc.x) | (f2bf(acc.y) << 16);
    o.y = f2bf(acc.z) | (f2bf(acc.w) << 16);
    __builtin_nontemporal_store(o, &xw[(size_t)wave * 64 + lane]);
}

// ---------------- SpMM2: out(f32) = relu( sparse(adj) @ xw(bf16) ) ----------

__global__ void spmm2(const int* __restrict__ offsets, const unsigned* __restrict__ edges,
                      const u32x2* __restrict__ xw, f32x4* __restrict__ out, int n) {
    const int wave = (int)((blockIdx.x * blockDim.x + threadIdx.x) >> 6);
    const int lane = (int)(threadIdx.x & 63);
    if (wave >= n) return;
    const int s = offsets[wave], e = offsets[wave + 1];

    float4 acc = make_float4(0.f, 0.f, 0.f, 0.f);
    int i = s;
    for (; i + 1 < e; i += 2) {
        const unsigned p0 = __builtin_nontemporal_load(&edges[i]);
        const unsigned p1 = __builtin_nontemporal_load(&edges[i + 1]);
        const u32x2 g0 = xw[(size_t)(p0 >> 15) * 64 + lane];
        const u32x2 g1 = xw[(size_t)(p1 >> 15) * 64 + lane];
        const float v0 = __uint_as_float((p0 & 0x7FFFu) << 16);
        const float v1 = __uint_as_float((p1 & 0x7FFFu) << 16);
        acc.x += v0 * __uint_as_float(g0.x << 16)          + v1 * __uint_as_float(g1.x << 16);
        acc.y += v0 * __uint_as_float(g0.x & 0xFFFF0000u)  + v1 * __uint_as_float(g1.x & 0xFFFF0000u);
        acc.z += v0 * __uint_as_float(g0.y << 16)          + v1 * __uint_as_float(g1.y << 16);
        acc.w += v0 * __uint_as_float(g0.y & 0xFFFF0000u)  + v1 * __uint_as_float(g1.y & 0xFFFF0000u);
    }
    if (i < e) {
        const unsigned p0 = __builtin_nontemporal_load(&edges[i]);
        const u32x2 g0 = xw[(size_t)(p0 >> 15) * 64 + lane];
        const float v0 = __uint_as_float((p0 & 0x7FFFu) << 16);
        acc.x += v0 * __uint_as_float(g0.x << 16);
        acc.y += v0 * __uint_as_float(g0.x & 0xFFFF0000u);
        acc.z += v0 * __uint_as_float(g0.y << 16);
        acc.w += v0 * __uint_as_float(g0.y & 0xFFFF0000u);
    }
    f32x4 o;
    o.x = fmaxf(acc.x, 0.f); o.y = fmaxf(acc.y, 0.f);
    o.z = fmaxf(acc.z, 0.f); o.w = fmaxf(acc.w, 0.f);
    __builtin_nontemporal_store(o, &out[(size_t)wave * 64 + lane]);
}

// ---------------- fallback (atomic) path ----------------

__global__ void spmm_scatter(const int* __restrict__ rows, const int* __restrict__ cols,
                             const float* __restrict__ vals, const float* __restrict__ src,
                             float* __restrict__ dst, int nnz) {
    const int lane  = threadIdx.x & 63;
    const int wave  = (int)((blockIdx.x * blockDim.x + threadIdx.x) >> 6);
    const int nwave = (int)((gridDim.x * blockDim.x) >> 6);
    for (int e = wave; e < nnz; e += nwave) {
        const int r = rows[e];
        const int c = cols[e];
        const float v = vals[e];
        const float4 w = reinterpret_cast<const float4*>(src + (size_t)c * OUT_DIM)[lane];
        float* d = dst + (size_t)r * OUT_DIM + (size_t)lane * 4;
        atomicAdd(d + 0, v * w.x);
        atomicAdd(d + 1, v * w.y);
        atomicAdd(d + 2, v * w.z);
        atomicAdd(d + 3, v * w.w);
    }
}

__global__ void relu_inplace_f4(float4* __restrict__ p, int n4) {
    int i = blockIdx.x * blockDim.x + threadIdx.x;
    int stride = gridDim.x * blockDim.x;
    for (; i < n4; i += stride) {
        float4 v = p[i];
        v.x = fmaxf(v.x, 0.f); v.y = fmaxf(v.y, 0.f);
        v.z = fmaxf(v.z, 0.f); v.w = fmaxf(v.w, 0.f);
        p[i] = v;
    }
}

// -----------------------------------------------------------------------------

static inline size_t al16(size_t x) { return (x + 15) & ~(size_t)15; }

extern "C" void kernel_launch(void* const* d_in, const int* in_sizes, int n_in,
                              void* d_out, int out_size, void* d_ws, size_t ws_size,
                              hipStream_t stream) {
    const int*   x_rows   = (const int*)  d_in[0];
    const int*   x_cols   = (const int*)  d_in[1];
    const float* x_vals   = (const float*)d_in[2];
    const int*   adj_rows = (const int*)  d_in[3];
    const int*   adj_cols = (const int*)  d_in[4];
    const float* adj_vals = (const float*)d_in[5];
    const float* W        = (const float*)d_in[6];

    const int nnz_x   = in_sizes[0];
    const int nnz_adj = in_sizes[3];
    const int N       = out_size / OUT_DIM;          // 100000
    const int IN_DIM  = in_sizes[6] / OUT_DIM;       // 1024
    const int nb      = (N + 1023) / 1024;           // scan chunks
    const int nnz_max = (nnz_x > nnz_adj) ? nnz_x : nnz_adj;

    float* out = (float*)d_out;
    char*  ws  = (char*)d_ws;

    // ---- workspace layout ----
    const size_t xw_bytes   = al16((size_t)N * OUT_DIM * 2);        // bf16 xw
    const size_t wb_bytes   = al16((size_t)IN_DIM * OUT_DIM * 2);   // bf16 W
    const size_t off_bytes  = al16((size_t)(N + 1) * 4);
    const size_t pos_bytes  = al16((size_t)N * 4);
    const size_t bsum_bytes = al16((size_t)nb * 4);
    const size_t q_bytes    = al16((size_t)nnz_max * 8);            // shared queue
    const size_t ex_bytes   = al16((size_t)nnz_x * 4);              // packed edges
    const size_t ea_bytes   = al16((size_t)nnz_adj * 4);
    const size_t qc_bytes   = al16((size_t)NPART * 4);
    const size_t need = xw_bytes + wb_bytes + 2 * off_bytes + 2 * pos_bytes
                      + 2 * bsum_bytes + q_bytes + ex_bytes + ea_bytes + 2 * qc_bytes;

    // Guards: partitions fit (N <= 8*16384), scan chunks fit, col fits pack.
    if (ws_size < need || nb > 1024 || N > (NPART << PSH) || N > (1 << 17) ||
        IN_DIM > (1 << 16)) {
        float* xwf = (float*)ws;
        (void)hipMemsetAsync(xwf, 0, (size_t)out_size * 4, stream);
        (void)hipMemsetAsync(out, 0, (size_t)out_size * 4, stream);
        spmm_scatter<<<8192, 256, 0, stream>>>(x_rows, x_cols, x_vals, W, xwf, nnz_x);
        spmm_scatter<<<8192, 256, 0, stream>>>(adj_rows, adj_cols, adj_vals, xwf, out, nnz_adj);
        relu_inplace_f4<<<2048, 256, 0, stream>>>((float4*)out, out_size / 4);
        return;
    }

    char* p = ws;
    u32x2*    xw      = (u32x2*)p;    p += xw_bytes;
    u32x2*    Wb      = (u32x2*)p;    p += wb_bytes;
    int*      off_x   = (int*)p;      p += off_bytes;
    int*      off_a   = (int*)p;      p += off_bytes;
    int*      pos_x   = (int*)p;      p += pos_bytes;
    int*      pos_a   = (int*)p;      p += pos_bytes;   // contiguous with pos_x
    int*      bsum_x  = (int*)p;      p += bsum_bytes;
    int*      bsum_a  = (int*)p;      p += bsum_bytes;
    u32x2*    q       = (u32x2*)p;    p += q_bytes;
    unsigned* edges_x = (unsigned*)p; p += ex_bytes;
    unsigned* edges_a = (unsigned*)p; p += ea_bytes;
    int*      qcur_x  = (int*)p;      p += qc_bytes;
    int*      qcur_a  = (int*)p;      p += qc_bytes;

    const int spmm_blocks = (N + 3) / 4;                   // 4 waves / block
    const int n_wb        = IN_DIM * (OUT_DIM / 4);        // u32x2 entries in Wb
    const int passA_x_blk = (nnz_x + 1023) / 1024;
    const int passA_a_blk = (nnz_adj + 1023) / 1024;

    // ---- CSR metadata (hist -> scan), merged for both matrices ----
    (void)hipMemsetAsync(pos_x, 0, pos_bytes + pos_bytes, stream);   // pos_x + pos_a
    hist2<<<4096, 256, 0, stream>>>(x_rows, nnz_x, pos_x, adj_rows, nnz_adj, pos_a);
    block_sums2<<<2 * nb, 256, 0, stream>>>(pos_x, pos_a, N, nb, bsum_x, bsum_a);
    scan_bsums2<<<2, 1024, 0, stream>>>(bsum_x, bsum_a, nb);
    scan_finalize2<<<2 * nb, 256, 0, stream>>>(pos_x, bsum_x, off_x, nnz_x,
                                               pos_a, bsum_a, off_a, nnz_adj, N, nb);
    prep<<<(n_wb + 255) / 256, 256, 0, stream>>>(W, Wb, n_wb, off_x, qcur_x,
                                                 off_a, qcur_a, N);

    // ---- sort x (queue shared -> serialized), then sort adj ----
    passA<false><<<passA_x_blk, 256, 0, stream>>>(x_rows, x_cols, x_vals, qcur_x, q, nnz_x);
    passB<<<4096, 256, 0, stream>>>(q, off_x, pos_x, edges_x, N);
    passA<true><<<passA_a_blk, 256, 0, stream>>>(adj_rows, adj_cols, adj_vals, qcur_a, q, nnz_adj);
    passB<<<4096, 256, 0, stream>>>(q, off_a, pos_a, edges_a, N);

    // ---- SpMMs ----
    spmm1<<<spmm_blocks, 256, 0, stream>>>(off_x, edges_x, Wb, xw, N);
    spmm2<<<spmm_blocks, 256, 0, stream>>>(off_a, edges_a, xw, (f32x4*)out, N);
}

// Round 10
// 919.890 us; speedup vs baseline: 1.1624x; 1.1624x over previous
//
#include <hip/hip_runtime.h>

// GCN sparse conv: out = relu( sparse(adj) @ ( sparse(x) @ W ) )
// Per matrix (serialized, shared 8B queue):
//   pack_hist: single read of rows/cols/vals -> q8 {row, packed_edge} + row hist
//   hierarchical scan -> CSR offsets + cursors
//   scatter8: 8-partition (XCD) filtered re-read of q8 (25.6MB, L3-hot);
//             each partition's writes land in an L2-resident ~1.6MB window.
// Then CSR SpMM: one 64-lane wave per row, register accumulation, no atomics.
// Edge words 4B: x = col<<16 | bf16(val); adj = col<<15 | bf15(val>=0).
// W converted to bf16 once. xw bf16 with PLAIN stores (stays L2-warm for
// spmm2's gather; NT store only for final out, which is never re-read).

constexpr int OUT_DIM = 256;
constexpr int NPART   = 8;      // XCD count

typedef float        f32x4 __attribute__((ext_vector_type(4)));
typedef unsigned int u32x2 __attribute__((ext_vector_type(2)));

static __device__ __forceinline__ unsigned f2bf(float f) {
    unsigned u = __float_as_uint(f);
    return (u + 0x7FFFu + ((u >> 16) & 1u)) >> 16;   // round-nearest-even
}

// ---------------- pack + histogram (one read of the COO triple) ----------------

template <bool ADJ>
__global__ void pack_hist(const int* __restrict__ rows, const int* __restrict__ cols,
                          const float* __restrict__ vals, int* __restrict__ cnt,
                          u32x2* __restrict__ q8, int nnz) {
    int i = blockIdx.x * blockDim.x + threadIdx.x;
    const int stride = gridDim.x * blockDim.x;
    for (; i < nnz; i += stride) {
        const int   r = rows[i];
        const int   c = cols[i];
        const float v = vals[i];
        u32x2 e;
        e.x = (unsigned)r;
        e.y = ADJ ? (((unsigned)c << 15) | (f2bf(v) & 0x7FFFu))
                  : (((unsigned)c << 16) | f2bf(v));
        q8[i] = e;
        atomicAdd(&cnt[r], 1);
    }
}

// ---------------- hierarchical scan (single matrix) ----------------

__global__ void block_sums(const int* __restrict__ counts, int n, int* __restrict__ bsum) {
    __shared__ int sh[256];
    const int b = blockIdx.x, t = threadIdx.x;
    const int idx = b * 1024 + t * 4;
    int s = 0;
    if (idx + 3 < n) {
        int4 v = *reinterpret_cast<const int4*>(counts + idx);
        s = v.x + v.y + v.z + v.w;
    } else {
        for (int k = 0; k < 4; ++k) if (idx + k < n) s += counts[idx + k];
    }
    sh[t] = s;
    __syncthreads();
    for (int off = 128; off > 0; off >>= 1) {
        if (t < off) sh[t] += sh[t + off];
        __syncthreads();
    }
    if (t == 0) bsum[b] = sh[0];
}

__global__ void scan_bsums(int* __restrict__ bsum, int nb) {
    __shared__ int sh[1024];
    const int t = threadIdx.x;
    const int v = (t < nb) ? bsum[t] : 0;
    sh[t] = v;
    __syncthreads();
    for (int off = 1; off < 1024; off <<= 1) {
        int cur = sh[t];
        int a = (t >= off) ? sh[t - off] : 0;
        __syncthreads();
        sh[t] = cur + a;
        __syncthreads();
    }
    if (t < nb) bsum[t] = sh[t] - v;   // exclusive
}

// counts/pos alias in place; writes offsets[] and cursors pos[].
__global__ void scan_finalize(int* __restrict__ pos, const int* __restrict__ boff,
                              int* __restrict__ offsets, int n, int nnz) {
    __shared__ int sh[256];
    const int b = blockIdx.x, t = threadIdx.x;
    const int idx = b * 1024 + t * 4;
    int c0 = 0, c1 = 0, c2 = 0, c3 = 0;
    if (idx + 3 < n) {
        int4 v = *reinterpret_cast<const int4*>(pos + idx);
        c0 = v.x; c1 = v.y; c2 = v.z; c3 = v.w;
    } else {
        if (idx + 0 < n) c0 = pos[idx + 0];
        if (idx + 1 < n) c1 = pos[idx + 1];
        if (idx + 2 < n) c2 = pos[idx + 2];
        if (idx + 3 < n) c3 = pos[idx + 3];
    }
    const int tsum = c0 + c1 + c2 + c3;
    sh[t] = tsum;
    __syncthreads();
    for (int off = 1; off < 256; off <<= 1) {
        int cur = sh[t];
        int a = (t >= off) ? sh[t - off] : 0;
        __syncthreads();
        sh[t] = cur + a;
        __syncthreads();
    }
    const int base = boff[b] + sh[t] - tsum;
    const int o0 = base, o1 = o0 + c0, o2 = o1 + c1, o3 = o2 + c2;
    if (idx + 3 < n) {
        *reinterpret_cast<int4*>(offsets + idx) = make_int4(o0, o1, o2, o3);
        *reinterpret_cast<int4*>(pos + idx)     = make_int4(o0, o1, o2, o3);
    } else {
        if (idx + 0 < n) { offsets[idx + 0] = o0; pos[idx + 0] = o0; }
        if (idx + 1 < n) { offsets[idx + 1] = o1; pos[idx + 1] = o1; }
        if (idx + 2 < n) { offsets[idx + 2] = o2; pos[idx + 2] = o2; }
        if (idx + 3 < n) { offsets[idx + 3] = o3; pos[idx + 3] = o3; }
    }
    if (b == 0 && t == 0) offsets[n] = nnz;
}

// ---------------- XCD-partitioned scatter from packed queue ----------------
// Partition p = blockIdx&7 (~XCD p) scans the whole q8 (L3-hot after pass 1)
// and scatters only rows in its 1/8 range: cursors + write window L2-resident.
__global__ void scatter8(const u32x2* __restrict__ q8, int* __restrict__ pos,
                         unsigned* __restrict__ edges, int nnz, int psize, int N) {
    const int part = (int)(blockIdx.x & (NPART - 1));
    const int lo   = part * psize;
    const int hi   = min(lo + psize, N);
    int i = (int)((blockIdx.x >> 3) * blockDim.x + threadIdx.x);
    const int stride = (int)((gridDim.x >> 3) * blockDim.x);
    for (; i < nnz; i += stride) {
        const u32x2 e = q8[i];
        const int   r = (int)e.x;
        if (r >= lo && r < hi) {
            const int s = atomicAdd(&pos[r], 1);
            edges[s] = e.y;
        }
    }
}

// ---------------- prep: W -> bf16 (u32x2 per 4 cols) ----------------

__global__ void prep_wb(const float* __restrict__ W, u32x2* __restrict__ Wb, int n_wb) {
    const int i = (int)(blockIdx.x * blockDim.x + threadIdx.x);
    if (i < n_wb) {
        const float4 w = reinterpret_cast<const float4*>(W)[i];
        u32x2 o;
        o.x = f2bf(w.x) | (f2bf(w.y) << 16);
        o.y = f2bf(w.z) | (f2bf(w.w) << 16);
        Wb[i] = o;
    }
}

// ---------------- SpMM1: xw(bf16) = sparse(x) @ Wb(bf16) ----------------

__global__ void spmm1(const int* __restrict__ offsets, const unsigned* __restrict__ edges,
                      const u32x2* __restrict__ Wb, u32x2* __restrict__ xw, int n) {
    const int wave = (int)((blockIdx.x * blockDim.x + threadIdx.x) >> 6);
    const int lane = (int)(threadIdx.x & 63);
    if (wave >= n) return;
    const int s = offsets[wave], e = offsets[wave + 1];

    float4 acc = make_float4(0.f, 0.f, 0.f, 0.f);
    int i = s;
    for (; i + 1 < e; i += 2) {
        const unsigned p0 = edges[i], p1 = edges[i + 1];
        const u32x2 g0 = Wb[(size_t)(p0 >> 16) * 64 + lane];
        const u32x2 g1 = Wb[(size_t)(p1 >> 16) * 64 + lane];
        const float v0 = __uint_as_float(p0 << 16);
        const float v1 = __uint_as_float(p1 << 16);
        acc.x += v0 * __uint_as_float(g0.x << 16)          + v1 * __uint_as_float(g1.x << 16);
        acc.y += v0 * __uint_as_float(g0.x & 0xFFFF0000u)  + v1 * __uint_as_float(g1.x & 0xFFFF0000u);
        acc.z += v0 * __uint_as_float(g0.y << 16)          + v1 * __uint_as_float(g1.y << 16);
        acc.w += v0 * __uint_as_float(g0.y & 0xFFFF0000u)  + v1 * __uint_as_float(g1.y & 0xFFFF0000u);
    }
    if (i < e) {
        const unsigned p0 = edges[i];
        const u32x2 g0 = Wb[(size_t)(p0 >> 16) * 64 + lane];
        const float v0 = __uint_as_float(p0 << 16);
        acc.x += v0 * __uint_as_float(g0.x << 16);
        acc.y += v0 * __uint_as_float(g0.x & 0xFFFF0000u);
        acc.z += v0 * __uint_as_float(g0.y << 16);
        acc.w += v0 * __uint_as_float(g0.y & 0xFFFF0000u);
    }
    u32x2 o;
    o.x = f2bf(acc.x) | (f2bf(acc.y) << 16);
    o.y = f2bf(acc.z) | (f2bf(acc.w) << 16);
    xw[(size_t)wave * 64 + lane] = o;            // plain store: keep L2-warm
}

// ---------------- SpMM2: out(f32) = relu( sparse(adj) @ xw(bf16) ) ----------
// 4-deep unroll: 4 independent gathers in flight per wave (MLP).

__global__ void spmm2(const int* __restrict__ offsets, const unsigned* __restrict__ edges,
                      const u32x2* __restrict__ xw, f32x4* __restrict__ out, int n) {
    const int wave = (int)((blockIdx.x * blockDim.x + threadIdx.x) >> 6);
    const int lane = (int)(threadIdx.x & 63);
    if (wave >= n) return;
    const int s = offsets[wave], e = offsets[wave + 1];

    float4 acc = make_float4(0.f, 0.f, 0.f, 0.f);
    int i = s;
    for (; i + 3 < e; i += 4) {
        const unsigned p0 = edges[i],     p1 = edges[i + 1];
        const unsigned p2 = edges[i + 2], p3 = edges[i + 3];
        const u32x2 g0 = xw[(size_t)(p0 >> 15) * 64 + lane];
        const u32x2 g1 = xw[(size_t)(p1 >> 15) * 64 + lane];
        const u32x2 g2 = xw[(size_t)(p2 >> 15) * 64 + lane];
        const u32x2 g3 = xw[(size_t)(p3 >> 15) * 64 + lane];
        const float v0 = __uint_as_float((p0 & 0x7FFFu) << 16);
        const float v1 = __uint_as_float((p1 & 0x7FFFu) << 16);
        const float v2 = __uint_as_float((p2 & 0x7FFFu) << 16);
        const float v3 = __uint_as_float((p3 & 0x7FFFu) << 16);
        acc.x += v0 * __uint_as_float(g0.x << 16)         + v1 * __uint_as_float(g1.x << 16)
               + v2 * __uint_as_float(g2.x << 16)         + v3 * __uint_as_float(g3.x << 16);
        acc.y += v0 * __uint_as_float(g0.x & 0xFFFF0000u) + v1 * __uint_as_float(g1.x & 0xFFFF0000u)
               + v2 * __uint_as_float(g2.x & 0xFFFF0000u) + v3 * __uint_as_float(g3.x & 0xFFFF0000u);
        acc.z += v0 * __uint_as_float(g0.y << 16)         + v1 * __uint_as_float(g1.y << 16)
               + v2 * __uint_as_float(g2.y << 16)         + v3 * __uint_as_float(g3.y << 16);
        acc.w += v0 * __uint_as_float(g0.y & 0xFFFF0000u) + v1 * __uint_as_float(g1.y & 0xFFFF0000u)
               + v2 * __uint_as_float(g2.y & 0xFFFF0000u) + v3 * __uint_as_float(g3.y & 0xFFFF0000u);
    }
    for (; i < e; ++i) {
        const unsigned p0 = edges[i];
        const u32x2 g0 = xw[(size_t)(p0 >> 15) * 64 + lane];
        const float v0 = __uint_as_float((p0 & 0x7FFFu) << 16);
        acc.x += v0 * __uint_as_float(g0.x << 16);
        acc.y += v0 * __uint_as_float(g0.x & 0xFFFF0000u);
        acc.z += v0 * __uint_as_float(g0.y << 16);
        acc.w += v0 * __uint_as_float(g0.y & 0xFFFF0000u);
    }
    f32x4 o;
    o.x = fmaxf(acc.x, 0.f); o.y = fmaxf(acc.y, 0.f);
    o.z = fmaxf(acc.z, 0.f); o.w = fmaxf(acc.w, 0.f);
    __builtin_nontemporal_store(o, &out[(size_t)wave * 64 + lane]);  // never re-read
}

// ---------------- fallback (atomic) path ----------------

__global__ void spmm_scatter(const int* __restrict__ rows, const int* __restrict__ cols,
                             const float* __restrict__ vals, const float* __restrict__ src,
                             float* __restrict__ dst, int nnz) {
    const int lane  = threadIdx.x & 63;
    const int wave  = (int)((blockIdx.x * blockDim.x + threadIdx.x) >> 6);
    const int nwave = (int)((gridDim.x * blockDim.x) >> 6);
    for (int e = wave; e < nnz; e += nwave) {
        const int r = rows[e];
        const int c = cols[e];
        const float v = vals[e];
        const float4 w = reinterpret_cast<const float4*>(src + (size_t)c * OUT_DIM)[lane];
        float* d = dst + (size_t)r * OUT_DIM + (size_t)lane * 4;
        atomicAdd(d + 0, v * w.x);
        atomicAdd(d + 1, v * w.y);
        atomicAdd(d + 2, v * w.z);
        atomicAdd(d + 3, v * w.w);
    }
}

__global__ void relu_inplace_f4(float4* __restrict__ p, int n4) {
    int i = blockIdx.x * blockDim.x + threadIdx.x;
    int stride = gridDim.x * blockDim.x;
    for (; i < n4; i += stride) {
        float4 v = p[i];
        v.x = fmaxf(v.x, 0.f); v.y = fmaxf(v.y, 0.f);
        v.z = fmaxf(v.z, 0.f); v.w = fmaxf(v.w, 0.f);
        p[i] = v;
    }
}

// -----------------------------------------------------------------------------

static inline size_t al16(size_t x) { return (x + 15) & ~(size_t)15; }

extern "C" void kernel_launch(void* const* d_in, const int* in_sizes, int n_in,
                              void* d_out, int out_size, void* d_ws, size_t ws_size,
                              hipStream_t stream) {
    const int*   x_rows   = (const int*)  d_in[0];
    const int*   x_cols   = (const int*)  d_in[1];
    const float* x_vals   = (const float*)d_in[2];
    const int*   adj_rows = (const int*)  d_in[3];
    const int*   adj_cols = (const int*)  d_in[4];
    const float* adj_vals = (const float*)d_in[5];
    const float* W        = (const float*)d_in[6];

    const int nnz_x   = in_sizes[0];
    const int nnz_adj = in_sizes[3];
    const int N       = out_size / OUT_DIM;          // 100000
    const int IN_DIM  = in_sizes[6] / OUT_DIM;       // 1024
    const int nb      = (N + 1023) / 1024;           // scan chunks
    const int psize   = (N + NPART - 1) / NPART;     // rows per XCD partition
    const int nnz_max = (nnz_x > nnz_adj) ? nnz_x : nnz_adj;

    float* out = (float*)d_out;
    char*  ws  = (char*)d_ws;

    // ---- workspace layout ----
    const size_t xw_bytes   = al16((size_t)N * OUT_DIM * 2);        // bf16 xw
    const size_t wb_bytes   = al16((size_t)IN_DIM * OUT_DIM * 2);   // bf16 W
    const size_t off_bytes  = al16((size_t)(N + 1) * 4);
    const size_t pos_bytes  = al16((size_t)N * 4);
    const size_t bsum_bytes = al16((size_t)nb * 4);
    const size_t q8_bytes   = al16((size_t)nnz_max * 8);            // shared packed queue
    const size_t ex_bytes   = al16((size_t)nnz_x * 4);              // final 4B edges
    const size_t ea_bytes   = al16((size_t)nnz_adj * 4);
    const size_t need = xw_bytes + wb_bytes + 2 * off_bytes + 2 * pos_bytes
                      + bsum_bytes + q8_bytes + ex_bytes + ea_bytes;

    if (ws_size < need || nb > 1024 || N > (1 << 17) || IN_DIM > (1 << 16)) {
        float* xwf = (float*)ws;
        (void)hipMemsetAsync(xwf, 0, (size_t)out_size * 4, stream);
        (void)hipMemsetAsync(out, 0, (size_t)out_size * 4, stream);
        spmm_scatter<<<8192, 256, 0, stream>>>(x_rows, x_cols, x_vals, W, xwf, nnz_x);
        spmm_scatter<<<8192, 256, 0, stream>>>(adj_rows, adj_cols, adj_vals, xwf, out, nnz_adj);
        relu_inplace_f4<<<2048, 256, 0, stream>>>((float4*)out, out_size / 4);
        return;
    }

    char* p = ws;
    u32x2*    xw      = (u32x2*)p;    p += xw_bytes;
    u32x2*    Wb      = (u32x2*)p;    p += wb_bytes;
    int*      off_x   = (int*)p;      p += off_bytes;
    int*      off_a   = (int*)p;      p += off_bytes;
    int*      pos_x   = (int*)p;      p += pos_bytes;
    int*      pos_a   = (int*)p;      p += pos_bytes;   // contiguous with pos_x
    int*      bsum    = (int*)p;      p += bsum_bytes;
    u32x2*    q8      = (u32x2*)p;    p += q8_bytes;
    unsigned* edges_x = (unsigned*)p; p += ex_bytes;
    unsigned* edges_a = (unsigned*)p; p += ea_bytes;

    const int spmm_blocks = (N + 3) / 4;                   // 4 waves / block
    const int n_wb        = IN_DIM * (OUT_DIM / 4);        // u32x2 entries in Wb

    (void)hipMemsetAsync(pos_x, 0, pos_bytes + pos_bytes, stream);   // pos_x + pos_a
    prep_wb<<<(n_wb + 255) / 256, 256, 0, stream>>>(W, Wb, n_wb);

    // ---- matrix x: pack+hist -> scan -> scatter ----
    pack_hist<false><<<2048, 256, 0, stream>>>(x_rows, x_cols, x_vals, pos_x, q8, nnz_x);
    block_sums<<<nb, 256, 0, stream>>>(pos_x, N, bsum);
    scan_bsums<<<1, 1024, 0, stream>>>(bsum, nb);
    scan_finalize<<<nb, 256, 0, stream>>>(pos_x, bsum, off_x, N, nnz_x);
    scatter8<<<4096, 256, 0, stream>>>(q8, pos_x, edges_x, nnz_x, psize, N);

    // ---- matrix adj (reuses q8) ----
    pack_hist<true><<<2048, 256, 0, stream>>>(adj_rows, adj_cols, adj_vals, pos_a, q8, nnz_adj);
    block_sums<<<nb, 256, 0, stream>>>(pos_a, N, bsum);
    scan_bsums<<<1, 1024, 0, stream>>>(bsum, nb);
    scan_finalize<<<nb, 256, 0, stream>>>(pos_a, bsum, off_a, N, nnz_adj);
    scatter8<<<4096, 256, 0, stream>>>(q8, pos_a, edges_a, nnz_adj, psize, N);

    // ---- SpMMs ----
    spmm1<<<spmm_blocks, 256, 0, stream>>>(off_x, edges_x, Wb, xw, N);
    spmm2<<<spmm_blocks, 256, 0, stream>>>(off_a, edges_a, xw, (f32x4*)out, N);
}

// Round 11
// 911.191 us; speedup vs baseline: 1.1735x; 1.0095x over previous
//
#include <hip/hip_runtime.h>

// GCN sparse conv: out = relu( sparse(adj) @ ( sparse(x) @ W ) )
// Pipeline (8 dispatches):
//   memset cursors
//   pack2: one pass over BOTH COO triples -> q8_{x,a} {row, packed_edge} +
//          row histograms; also converts W -> bf16 (tail of grid-stride).
//   merged hierarchical scan (block_sums2 / scan_bsums2 / scan_finalize2)
//   scatter2: grid halves = {x, adj}; 8-partition (XCD) filtered re-read of
//             q8 (NT loads, L3-served); writes land in L2-resident window.
//   spmm1, spmm2: CSR SpMM, one 64-lane wave per row, register accumulation.
// Edge words 4B: x = col<<16 | bf16(val); adj = col<<15 | bf15(val>=0).
// xw bf16 with PLAIN stores (L2-warm for spmm2); NT stores only for final out.

constexpr int OUT_DIM = 256;
constexpr int NPART   = 8;      // XCD count

typedef float        f32x4 __attribute__((ext_vector_type(4)));
typedef unsigned int u32x2 __attribute__((ext_vector_type(2)));

static __device__ __forceinline__ unsigned f2bf(float f) {
    unsigned u = __float_as_uint(f);
    return (u + 0x7FFFu + ((u >> 16) & 1u)) >> 16;   // round-nearest-even
}

// ------- pack both matrices (+W->bf16) in one grid-stride pass -------

__global__ void pack2(const int* __restrict__ xr, const int* __restrict__ xc,
                      const float* __restrict__ xv, int nx, int* __restrict__ cx,
                      u32x2* __restrict__ qx,
                      const int* __restrict__ ar, const int* __restrict__ ac,
                      const float* __restrict__ av, int na, int* __restrict__ ca,
                      u32x2* __restrict__ qa,
                      const float* __restrict__ W, u32x2* __restrict__ Wb, int n_wb) {
    int i = blockIdx.x * blockDim.x + threadIdx.x;
    const int stride = gridDim.x * blockDim.x;
    const int tot = nx + na + n_wb;
    for (; i < tot; i += stride) {
        if (i < nx) {
            const int   r = __builtin_nontemporal_load(&xr[i]);
            const int   c = __builtin_nontemporal_load(&xc[i]);
            const float v = __builtin_nontemporal_load(&xv[i]);
            u32x2 e; e.x = (unsigned)r; e.y = ((unsigned)c << 16) | f2bf(v);
            __builtin_nontemporal_store(e, &qx[i]);
            atomicAdd(&cx[r], 1);
        } else if (i < nx + na) {
            const int   j = i - nx;
            const int   r = __builtin_nontemporal_load(&ar[j]);
            const int   c = __builtin_nontemporal_load(&ac[j]);
            const float v = __builtin_nontemporal_load(&av[j]);
            u32x2 e; e.x = (unsigned)r; e.y = ((unsigned)c << 15) | (f2bf(v) & 0x7FFFu);
            __builtin_nontemporal_store(e, &qa[j]);
            atomicAdd(&ca[r], 1);
        } else {
            const int j = i - nx - na;
            const float4 w = reinterpret_cast<const float4*>(W)[j];
            u32x2 o;
            o.x = f2bf(w.x) | (f2bf(w.y) << 16);
            o.y = f2bf(w.z) | (f2bf(w.w) << 16);
            Wb[j] = o;
        }
    }
}

// ------- merged hierarchical scan (x + adj) -------

__global__ void block_sums2(const int* __restrict__ cx, const int* __restrict__ ca,
                            int n, int nb, int* __restrict__ bx, int* __restrict__ ba) {
    __shared__ int sh[256];
    int b = (int)blockIdx.x;
    const int* counts; int* bs;
    if (b < nb) { counts = cx; bs = bx; } else { counts = ca; bs = ba; b -= nb; }
    const int t = threadIdx.x;
    const int idx = b * 1024 + t * 4;
    int s = 0;
    if (idx + 3 < n) {
        int4 v = *reinterpret_cast<const int4*>(counts + idx);
        s = v.x + v.y + v.z + v.w;
    } else {
        for (int k = 0; k < 4; ++k) if (idx + k < n) s += counts[idx + k];
    }
    sh[t] = s;
    __syncthreads();
    for (int off = 128; off > 0; off >>= 1) {
        if (t < off) sh[t] += sh[t + off];
        __syncthreads();
    }
    if (t == 0) bs[b] = sh[0];
}

__global__ void scan_bsums2(int* __restrict__ bx, int* __restrict__ ba, int nb) {
    __shared__ int sh[1024];
    int* bs = (blockIdx.x == 0) ? bx : ba;
    const int t = threadIdx.x;
    const int v = (t < nb) ? bs[t] : 0;
    sh[t] = v;
    __syncthreads();
    for (int off = 1; off < 1024; off <<= 1) {
        int cur = sh[t];
        int a = (t >= off) ? sh[t - off] : 0;
        __syncthreads();
        sh[t] = cur + a;
        __syncthreads();
    }
    if (t < nb) bs[t] = sh[t] - v;   // exclusive
}

__global__ void scan_finalize2(int* __restrict__ px, const int* __restrict__ bx,
                               int* __restrict__ ox, int nnzx,
                               int* __restrict__ pa, const int* __restrict__ ba,
                               int* __restrict__ oa, int nnza,
                               int n, int nb) {
    __shared__ int sh[256];
    int b = (int)blockIdx.x;
    int* pos; const int* boff; int* offsets; int nnz;
    if (b < nb) { pos = px; boff = bx; offsets = ox; nnz = nnzx; }
    else        { pos = pa; boff = ba; offsets = oa; nnz = nnza; b -= nb; }
    const int t = threadIdx.x;
    const int idx = b * 1024 + t * 4;
    int c0 = 0, c1 = 0, c2 = 0, c3 = 0;
    if (idx + 3 < n) {
        int4 v = *reinterpret_cast<const int4*>(pos + idx);
        c0 = v.x; c1 = v.y; c2 = v.z; c3 = v.w;
    } else {
        if (idx + 0 < n) c0 = pos[idx + 0];
        if (idx + 1 < n) c1 = pos[idx + 1];
        if (idx + 2 < n) c2 = pos[idx + 2];
        if (idx + 3 < n) c3 = pos[idx + 3];
    }
    const int tsum = c0 + c1 + c2 + c3;
    sh[t] = tsum;
    __syncthreads();
    for (int off = 1; off < 256; off <<= 1) {
        int cur = sh[t];
        int a = (t >= off) ? sh[t - off] : 0;
        __syncthreads();
        sh[t] = cur + a;
        __syncthreads();
    }
    const int base = boff[b] + sh[t] - tsum;
    const int o0 = base, o1 = o0 + c0, o2 = o1 + c1, o3 = o2 + c2;
    if (idx + 3 < n) {
        *reinterpret_cast<int4*>(offsets + idx) = make_int4(o0, o1, o2, o3);
        *reinterpret_cast<int4*>(pos + idx)     = make_int4(o0, o1, o2, o3);
    } else {
        if (idx + 0 < n) { offsets[idx + 0] = o0; pos[idx + 0] = o0; }
        if (idx + 1 < n) { offsets[idx + 1] = o1; pos[idx + 1] = o1; }
        if (idx + 2 < n) { offsets[idx + 2] = o2; pos[idx + 2] = o2; }
        if (idx + 3 < n) { offsets[idx + 3] = o3; pos[idx + 3] = o3; }
    }
    if (b == 0 && t == 0) offsets[n] = nnz;
}

// ------- merged XCD-partitioned scatter (grid halves = x, adj) -------

__global__ void scatter2(const u32x2* __restrict__ qx, int nx, int* __restrict__ pos_x,
                         unsigned* __restrict__ ex,
                         const u32x2* __restrict__ qa, int na, int* __restrict__ pos_a,
                         unsigned* __restrict__ ea, int psize, int N) {
    const unsigned half = gridDim.x >> 1;           // multiple of 8
    const bool     adj  = (blockIdx.x >= half);
    const int      lb   = (int)(adj ? blockIdx.x - half : blockIdx.x);
    const int      part = lb & (NPART - 1);
    const int      lo   = part * psize;
    const int      hi   = min(lo + psize, N);
    const u32x2* __restrict__ q = adj ? qa : qx;
    const int nnz = adj ? na : nx;
    int* __restrict__ pos = adj ? pos_a : pos_x;
    unsigned* __restrict__ edges = adj ? ea : ex;

    int i = (lb >> 3) * (int)blockDim.x + (int)threadIdx.x;
    const int stride = (int)((half >> 3) * blockDim.x);
    for (; i < nnz; i += stride) {
        const u32x2 e = __builtin_nontemporal_load(&q[i]);
        const int   r = (int)e.x;
        if (r >= lo && r < hi) {
            const int s = atomicAdd(&pos[r], 1);
            edges[s] = e.y;
        }
    }
}

// ------- SpMM1: xw(bf16) = sparse(x) @ Wb(bf16), W L2-hot -------

__global__ void spmm1(const int* __restrict__ offsets, const unsigned* __restrict__ edges,
                      const u32x2* __restrict__ Wb, u32x2* __restrict__ xw, int n) {
    const int wave = (int)((blockIdx.x * blockDim.x + threadIdx.x) >> 6);
    const int lane = (int)(threadIdx.x & 63);
    if (wave >= n) return;
    const int s = offsets[wave], e = offsets[wave + 1];

    float4 acc = make_float4(0.f, 0.f, 0.f, 0.f);
    int i = s;
    for (; i + 3 < e; i += 4) {
        const unsigned p0 = __builtin_nontemporal_load(&edges[i]);
        const unsigned p1 = __builtin_nontemporal_load(&edges[i + 1]);
        const unsigned p2 = __builtin_nontemporal_load(&edges[i + 2]);
        const unsigned p3 = __builtin_nontemporal_load(&edges[i + 3]);
        const u32x2 g0 = Wb[(size_t)(p0 >> 16) * 64 + lane];
        const u32x2 g1 = Wb[(size_t)(p1 >> 16) * 64 + lane];
        const u32x2 g2 = Wb[(size_t)(p2 >> 16) * 64 + lane];
        const u32x2 g3 = Wb[(size_t)(p3 >> 16) * 64 + lane];
        const float v0 = __uint_as_float(p0 << 16);
        const float v1 = __uint_as_float(p1 << 16);
        const float v2 = __uint_as_float(p2 << 16);
        const float v3 = __uint_as_float(p3 << 16);
        acc.x += v0 * __uint_as_float(g0.x << 16)         + v1 * __uint_as_float(g1.x << 16)
               + v2 * __uint_as_float(g2.x << 16)         + v3 * __uint_as_float(g3.x << 16);
        acc.y += v0 * __uint_as_float(g0.x & 0xFFFF0000u) + v1 * __uint_as_float(g1.x & 0xFFFF0000u)
               + v2 * __uint_as_float(g2.x & 0xFFFF0000u) + v3 * __uint_as_float(g3.x & 0xFFFF0000u);
        acc.z += v0 * __uint_as_float(g0.y << 16)         + v1 * __uint_as_float(g1.y << 16)
               + v2 * __uint_as_float(g2.y << 16)         + v3 * __uint_as_float(g3.y << 16);
        acc.w += v0 * __uint_as_float(g0.y & 0xFFFF0000u) + v1 * __uint_as_float(g1.y & 0xFFFF0000u)
               + v2 * __uint_as_float(g2.y & 0xFFFF0000u) + v3 * __uint_as_float(g3.y & 0xFFFF0000u);
    }
    for (; i < e; ++i) {
        const unsigned p0 = __builtin_nontemporal_load(&edges[i]);
        const u32x2 g0 = Wb[(size_t)(p0 >> 16) * 64 + lane];
        const float v0 = __uint_as_float(p0 << 16);
        acc.x += v0 * __uint_as_float(g0.x << 16);
        acc.y += v0 * __uint_as_float(g0.x & 0xFFFF0000u);
        acc.z += v0 * __uint_as_float(g0.y << 16);
        acc.w += v0 * __uint_as_float(g0.y & 0xFFFF0000u);
    }
    u32x2 o;
    o.x = f2bf(acc.x) | (f2bf(acc.y) << 16);
    o.y = f2bf(acc.z) | (f2bf(acc.w) << 16);
    xw[(size_t)wave * 64 + lane] = o;            // plain store: keep L2-warm
}

// ------- SpMM2: out(f32) = relu( sparse(adj) @ xw(bf16) ), 8-deep MLP -------

__global__ void spmm2(const int* __restrict__ offsets, const unsigned* __restrict__ edges,
                      const u32x2* __restrict__ xw, f32x4* __restrict__ out, int n) {
    const int wave = (int)((blockIdx.x * blockDim.x + threadIdx.x) >> 6);
    const int lane = (int)(threadIdx.x & 63);
    if (wave >= n) return;
    const int s = offsets[wave], e = offsets[wave + 1];

    float4 acc = make_float4(0.f, 0.f, 0.f, 0.f);
    int i = s;
    for (; i + 7 < e; i += 8) {
        unsigned p[8];
        #pragma unroll
        for (int k = 0; k < 8; ++k) p[k] = __builtin_nontemporal_load(&edges[i + k]);
        u32x2 g[8];
        #pragma unroll
        for (int k = 0; k < 8; ++k) g[k] = xw[(size_t)(p[k] >> 15) * 64 + lane];
        #pragma unroll
        for (int k = 0; k < 8; ++k) {
            const float v = __uint_as_float((p[k] & 0x7FFFu) << 16);
            acc.x += v * __uint_as_float(g[k].x << 16);
            acc.y += v * __uint_as_float(g[k].x & 0xFFFF0000u);
            acc.z += v * __uint_as_float(g[k].y << 16);
            acc.w += v * __uint_as_float(g[k].y & 0xFFFF0000u);
        }
    }
    for (; i < e; ++i) {
        const unsigned p0 = __builtin_nontemporal_load(&edges[i]);
        const u32x2 g0 = xw[(size_t)(p0 >> 15) * 64 + lane];
        const float v0 = __uint_as_float((p0 & 0x7FFFu) << 16);
        acc.x += v0 * __uint_as_float(g0.x << 16);
        acc.y += v0 * __uint_as_float(g0.x & 0xFFFF0000u);
        acc.z += v0 * __uint_as_float(g0.y << 16);
        acc.w += v0 * __uint_as_float(g0.y & 0xFFFF0000u);
    }
    f32x4 o;
    o.x = fmaxf(acc.x, 0.f); o.y = fmaxf(acc.y, 0.f);
    o.z = fmaxf(acc.z, 0.f); o.w = fmaxf(acc.w, 0.f);
    __builtin_nontemporal_store(o, &out[(size_t)wave * 64 + lane]);  // never re-read
}

// ---------------- fallback (atomic) path ----------------

__global__ void spmm_scatter(const int* __restrict__ rows, const int* __restrict__ cols,
                             const float* __restrict__ vals, const float* __restrict__ src,
                             float* __restrict__ dst, int nnz) {
    const int lane  = threadIdx.x & 63;
    const int wave  = (int)((blockIdx.x * blockDim.x + threadIdx.x) >> 6);
    const int nwave = (int)((gridDim.x * blockDim.x) >> 6);
    for (int e = wave; e < nnz; e += nwave) {
        const int r = rows[e];
        const int c = cols[e];
        const float v = vals[e];
        const float4 w = reinterpret_cast<const float4*>(src + (size_t)c * OUT_DIM)[lane];
        float* d = dst + (size_t)r * OUT_DIM + (size_t)lane * 4;
        atomicAdd(d + 0, v * w.x);
        atomicAdd(d + 1, v * w.y);
        atomicAdd(d + 2, v * w.z);
        atomicAdd(d + 3, v * w.w);
    }
}

__global__ void relu_inplace_f4(float4* __restrict__ p, int n4) {
    int i = blockIdx.x * blockDim.x + threadIdx.x;
    int stride = gridDim.x * blockDim.x;
    for (; i < n4; i += stride) {
        float4 v = p[i];
        v.x = fmaxf(v.x, 0.f); v.y = fmaxf(v.y, 0.f);
        v.z = fmaxf(v.z, 0.f); v.w = fmaxf(v.w, 0.f);
        p[i] = v;
    }
}

// -----------------------------------------------------------------------------

static inline size_t al16(size_t x) { return (x + 15) & ~(size_t)15; }

extern "C" void kernel_launch(void* const* d_in, const int* in_sizes, int n_in,
                              void* d_out, int out_size, void* d_ws, size_t ws_size,
                              hipStream_t stream) {
    const int*   x_rows   = (const int*)  d_in[0];
    const int*   x_cols   = (const int*)  d_in[1];
    const float* x_vals   = (const float*)d_in[2];
    const int*   adj_rows = (const int*)  d_in[3];
    const int*   adj_cols = (const int*)  d_in[4];
    const float* adj_vals = (const float*)d_in[5];
    const float* W        = (const float*)d_in[6];

    const int nnz_x   = in_sizes[0];
    const int nnz_adj = in_sizes[3];
    const int N       = out_size / OUT_DIM;          // 100000
    const int IN_DIM  = in_sizes[6] / OUT_DIM;       // 1024
    const int nb      = (N + 1023) / 1024;           // scan chunks
    const int psize   = (N + NPART - 1) / NPART;     // rows per XCD partition

    float* out = (float*)d_out;
    char*  ws  = (char*)d_ws;

    // ---- workspace layout ----
    const size_t xw_bytes   = al16((size_t)N * OUT_DIM * 2);        // bf16 xw
    const size_t wb_bytes   = al16((size_t)IN_DIM * OUT_DIM * 2);   // bf16 W
    const size_t off_bytes  = al16((size_t)(N + 1) * 4);
    const size_t pos_bytes  = al16((size_t)N * 4);
    const size_t bsum_bytes = al16((size_t)nb * 4);
    const size_t qx_bytes   = al16((size_t)nnz_x * 8);
    const size_t qa_bytes   = al16((size_t)nnz_adj * 8);
    const size_t ex_bytes   = al16((size_t)nnz_x * 4);
    const size_t ea_bytes   = al16((size_t)nnz_adj * 4);
    const size_t need = xw_bytes + wb_bytes + 2 * off_bytes + 2 * pos_bytes
                      + 2 * bsum_bytes + qx_bytes + qa_bytes + ex_bytes + ea_bytes;

    if (ws_size < need || nb > 1024 || N > (1 << 17) || IN_DIM > (1 << 16)) {
        float* xwf = (float*)ws;
        (void)hipMemsetAsync(xwf, 0, (size_t)out_size * 4, stream);
        (void)hipMemsetAsync(out, 0, (size_t)out_size * 4, stream);
        spmm_scatter<<<8192, 256, 0, stream>>>(x_rows, x_cols, x_vals, W, xwf, nnz_x);
        spmm_scatter<<<8192, 256, 0, stream>>>(adj_rows, adj_cols, adj_vals, xwf, out, nnz_adj);
        relu_inplace_f4<<<2048, 256, 0, stream>>>((float4*)out, out_size / 4);
        return;
    }

    char* p = ws;
    u32x2*    xw      = (u32x2*)p;    p += xw_bytes;
    u32x2*    Wb      = (u32x2*)p;    p += wb_bytes;
    int*      off_x   = (int*)p;      p += off_bytes;
    int*      off_a   = (int*)p;      p += off_bytes;
    int*      pos_x   = (int*)p;      p += pos_bytes;
    int*      pos_a   = (int*)p;      p += pos_bytes;   // contiguous with pos_x
    int*      bsum_x  = (int*)p;      p += bsum_bytes;
    int*      bsum_a  = (int*)p;      p += bsum_bytes;
    u32x2*    qx      = (u32x2*)p;    p += qx_bytes;
    u32x2*    qa      = (u32x2*)p;    p += qa_bytes;
    unsigned* edges_x = (unsigned*)p; p += ex_bytes;
    unsigned* edges_a = (unsigned*)p; p += ea_bytes;

    const int spmm_blocks = (N + 3) / 4;                   // 4 waves / block
    const int n_wb        = IN_DIM * (OUT_DIM / 4);        // u32x2 entries in Wb

    // ---- build CSR (both matrices together) ----
    (void)hipMemsetAsync(pos_x, 0, pos_bytes + pos_bytes, stream);   // pos_x + pos_a
    pack2<<<4096, 256, 0, stream>>>(x_rows, x_cols, x_vals, nnz_x, pos_x, qx,
                                    adj_rows, adj_cols, adj_vals, nnz_adj, pos_a, qa,
                                    W, Wb, n_wb);
    block_sums2<<<2 * nb, 256, 0, stream>>>(pos_x, pos_a, N, nb, bsum_x, bsum_a);
    scan_bsums2<<<2, 1024, 0, stream>>>(bsum_x, bsum_a, nb);
    scan_finalize2<<<2 * nb, 256, 0, stream>>>(pos_x, bsum_x, off_x, nnz_x,
                                               pos_a, bsum_a, off_a, nnz_adj, N, nb);
    scatter2<<<8192, 256, 0, stream>>>(qx, nnz_x, pos_x, edges_x,
                                       qa, nnz_adj, pos_a, edges_a, psize, N);

    // ---- SpMMs ----
    spmm1<<<spmm_blocks, 256, 0, stream>>>(off_x, edges_x, Wb, xw, N);
    spmm2<<<spmm_blocks, 256, 0, stream>>>(off_a, edges_a, xw, (f32x4*)out, N);
}

// Round 12
// 598.952 us; speedup vs baseline: 1.7853x; 1.5213x over previous
//
#include <hip/hip_runtime.h>

// GCN sparse conv: out = relu( sparse(adj) @ ( sparse(x) @ W ) )
// Bucket-granular counting sort (256 rows/bucket):
//   bhist2:   LDS-aggregated bucket histogram for both matrices (+W->bf16)
//   bscan2:   exclusive scan of bucket counts -> bases + global cursors
//   bscatter: 4096-edge chunks; LDS hist -> ONE global fetch-add per
//             (block,bucket); LDS re-rank + stage; bucket-ordered coalesced
//             flush. COO read once; ~2x write amplification (runs ~10 edges).
//   bfinal:   one block per bucket: per-row LDS count/scan/re-rank in a 32KB
//             L2-resident region -> CSR offsets + packed 4B edges.
// SpMM: one 64-lane wave per row, register accumulation, no atomics.
// Edge words 4B: x = col<<16 | bf16(val); adj = col<<15 | bf15(val>=0).
// xw bf16, plain stores (L2-warm for spmm2); NT stores only for final out.

constexpr int OUT_DIM = 256;
constexpr int RPB     = 256;     // rows per bucket
constexpr int RPB_SH  = 8;
constexpr int MAXB    = 1024;    // max buckets (N <= 262144)
constexpr int CHUNK   = 4096;    // edges per bscatter block

typedef float        f32x4 __attribute__((ext_vector_type(4)));
typedef unsigned int u32x2 __attribute__((ext_vector_type(2)));

static __device__ __forceinline__ unsigned f2bf(float f) {
    unsigned u = __float_as_uint(f);
    return (u + 0x7FFFu + ((u >> 16) & 1u)) >> 16;   // round-nearest-even
}

// ------- bucket histogram (both matrices) + W->bf16 -------

__global__ void bhist2(const int* __restrict__ xr, int nx,
                       const int* __restrict__ ar, int na,
                       int* __restrict__ bcx, int* __restrict__ bca,
                       const float* __restrict__ W, u32x2* __restrict__ Wb,
                       int n_wb, int nbk) {
    __shared__ int hx[MAXB], ha[MAXB];
    const int t = (int)threadIdx.x;
    for (int j = t; j < nbk; j += 256) { hx[j] = 0; ha[j] = 0; }
    __syncthreads();
    int i = (int)(blockIdx.x * blockDim.x + threadIdx.x);
    const int stride = (int)(gridDim.x * blockDim.x);
    const int tot = nx + na + n_wb;
    for (; i < tot; i += stride) {
        if (i < nx) {
            atomicAdd(&hx[__builtin_nontemporal_load(&xr[i]) >> RPB_SH], 1);
        } else if (i < nx + na) {
            atomicAdd(&ha[__builtin_nontemporal_load(&ar[i - nx]) >> RPB_SH], 1);
        } else {
            const int j = i - nx - na;
            const float4 w = reinterpret_cast<const float4*>(W)[j];
            u32x2 o;
            o.x = f2bf(w.x) | (f2bf(w.y) << 16);
            o.y = f2bf(w.z) | (f2bf(w.w) << 16);
            Wb[j] = o;
        }
    }
    __syncthreads();
    for (int j = t; j < nbk; j += 256) {
        if (hx[j]) atomicAdd(&bcx[j], hx[j]);
        if (ha[j]) atomicAdd(&bca[j], ha[j]);
    }
}

// ------- exclusive scan of bucket counts (in place) + cursor init -------
// block 0 -> x, block 1 -> adj.

__global__ void bscan2(int* __restrict__ bx, int* __restrict__ ba,
                       int* __restrict__ gx, int* __restrict__ ga, int nbk) {
    __shared__ int sh[MAXB];
    int* bs = (blockIdx.x == 0) ? bx : ba;
    int* gc = (blockIdx.x == 0) ? gx : ga;
    const int t = (int)threadIdx.x;
    const int v = (t < nbk) ? bs[t] : 0;
    sh[t] = v;
    __syncthreads();
    for (int off = 1; off < MAXB; off <<= 1) {
        int cur = sh[t];
        int a = (t >= off) ? sh[t - off] : 0;
        __syncthreads();
        sh[t] = cur + a;
        __syncthreads();
    }
    if (t < nbk) {
        const int e = sh[t] - v;   // exclusive
        bs[t] = e;
        gc[t] = e;
    }
}

// ------- aggregated bucket scatter: COO -> bucket-grouped q8 -------
// q entry: .x = rowInBucket(8b)<<17 | col(17b);  .y = f32 val bits.

__global__ void bscatter(const int* __restrict__ rows, const int* __restrict__ cols,
                         const float* __restrict__ vals, int* __restrict__ gcur,
                         u32x2* __restrict__ q, int nnz, int nbk) {
    __shared__ u32x2 stage[CHUNK];          // 32 KB
    __shared__ int   saddr[CHUNK];          // 16 KB
    __shared__ int   lcnt[MAXB], lstart[MAXB], gstart[MAXB];   // 12 KB
    __shared__ int   ssum[256];
    const int t    = (int)threadIdx.x;
    const int base = (int)blockIdx.x * CHUNK;
    const int cnt  = min(CHUNK, nnz - base);

    for (int j = t; j < nbk; j += 256) lcnt[j] = 0;
    __syncthreads();

    unsigned ex[16], ey[16];
    int my[16], bk[16];
    #pragma unroll
    for (int k = 0; k < 16; ++k) {
        const int i = base + k * 256 + t;
        bk[k] = -1;
        if (i < nnz) {
            const int   r = __builtin_nontemporal_load(&rows[i]);
            const int   c = __builtin_nontemporal_load(&cols[i]);
            const float v = __builtin_nontemporal_load(&vals[i]);
            bk[k] = r >> RPB_SH;
            ex[k] = ((unsigned)(r & (RPB - 1)) << 17) | (unsigned)c;
            ey[k] = __float_as_uint(v);
            my[k] = atomicAdd(&lcnt[bk[k]], 1);
        }
    }
    __syncthreads();

    // local exclusive scan of lcnt -> lstart (4 entries/thread over MAXB)
    {
        const int idx = t * 4;
        const int c0 = (idx + 0 < nbk) ? lcnt[idx + 0] : 0;
        const int c1 = (idx + 1 < nbk) ? lcnt[idx + 1] : 0;
        const int c2 = (idx + 2 < nbk) ? lcnt[idx + 2] : 0;
        const int c3 = (idx + 3 < nbk) ? lcnt[idx + 3] : 0;
        const int tsum = c0 + c1 + c2 + c3;
        ssum[t] = tsum;
        __syncthreads();
        for (int off = 1; off < 256; off <<= 1) {
            int cur = ssum[t];
            int a = (t >= off) ? ssum[t - off] : 0;
            __syncthreads();
            ssum[t] = cur + a;
            __syncthreads();
        }
        const int b0 = ssum[t] - tsum;
        lstart[idx + 0] = b0;
        lstart[idx + 1] = b0 + c0;
        lstart[idx + 2] = b0 + c0 + c1;
        lstart[idx + 3] = b0 + c0 + c1 + c2;
    }
    // global allocation: one fetch-add per nonempty (block,bucket)
    for (int j = t; j < nbk; j += 256) {
        const int c = lcnt[j];
        gstart[j] = c ? atomicAdd(&gcur[j], c) : 0;
    }
    __syncthreads();

    #pragma unroll
    for (int k = 0; k < 16; ++k) {
        if (bk[k] >= 0) {
            const int slot = lstart[bk[k]] + my[k];
            u32x2 e; e.x = ex[k]; e.y = ey[k];
            stage[slot] = e;
            saddr[slot] = gstart[bk[k]] + my[k];
        }
    }
    __syncthreads();
    // bucket-ordered flush: consecutive slots -> consecutive addresses per run
    for (int s = t; s < cnt; s += 256)
        q[saddr[s]] = stage[s];
}

// ------- per-bucket finalize: CSR offsets + packed 4B edges -------

template <bool ADJ>
__global__ void bfinal(const u32x2* __restrict__ q, const int* __restrict__ bbase,
                       unsigned* __restrict__ edges, int* __restrict__ offsets,
                       int N, int nnz, int nbk) {
    __shared__ int cnt[RPB], cur[RPB];
    const int b  = (int)blockIdx.x;
    const int t  = (int)threadIdx.x;
    const int gb = bbase[b];
    const int ge = (b + 1 < nbk) ? bbase[b + 1] : nnz;

    cnt[t] = 0;
    __syncthreads();
    for (int i = gb + t; i < ge; i += 256)
        atomicAdd(&cnt[q[i].x >> 17], 1);
    __syncthreads();

    // inclusive scan of cnt (256 threads, 1 elem each)
    const int c = cnt[t];
    cur[t] = c;
    __syncthreads();
    for (int off = 1; off < 256; off <<= 1) {
        int v = cur[t];
        int a = (t >= off) ? cur[t - off] : 0;
        __syncthreads();
        cur[t] = v + a;
        __syncthreads();
    }
    const int excl = cur[t] - c;
    const int r = b * RPB + t;
    if (r < N) offsets[r] = gb + excl;
    if (b == nbk - 1 && t == 0) offsets[N] = nnz;
    __syncthreads();
    cur[t] = gb + excl;          // reuse as per-row cursor
    __syncthreads();

    for (int i = gb + t; i < ge; i += 256) {
        const u32x2 e = q[i];
        const int rank = atomicAdd(&cur[e.x >> 17], 1);
        const unsigned col = e.x & 0x1FFFFu;
        const float v = __uint_as_float(e.y);
        edges[rank] = ADJ ? ((col << 15) | (f2bf(v) & 0x7FFFu))
                          : ((col << 16) | f2bf(v));
    }
}

// ------- SpMM1: xw(bf16) = sparse(x) @ Wb(bf16), W L2-hot -------

__global__ void spmm1(const int* __restrict__ offsets, const unsigned* __restrict__ edges,
                      const u32x2* __restrict__ Wb, u32x2* __restrict__ xw, int n) {
    const int wave = (int)((blockIdx.x * blockDim.x + threadIdx.x) >> 6);
    const int lane = (int)(threadIdx.x & 63);
    if (wave >= n) return;
    const int s = offsets[wave], e = offsets[wave + 1];

    float4 acc = make_float4(0.f, 0.f, 0.f, 0.f);
    int i = s;
    for (; i + 3 < e; i += 4) {
        const unsigned p0 = __builtin_nontemporal_load(&edges[i]);
        const unsigned p1 = __builtin_nontemporal_load(&edges[i + 1]);
        const unsigned p2 = __builtin_nontemporal_load(&edges[i + 2]);
        const unsigned p3 = __builtin_nontemporal_load(&edges[i + 3]);
        const u32x2 g0 = Wb[(size_t)(p0 >> 16) * 64 + lane];
        const u32x2 g1 = Wb[(size_t)(p1 >> 16) * 64 + lane];
        const u32x2 g2 = Wb[(size_t)(p2 >> 16) * 64 + lane];
        const u32x2 g3 = Wb[(size_t)(p3 >> 16) * 64 + lane];
        const float v0 = __uint_as_float(p0 << 16);
        const float v1 = __uint_as_float(p1 << 16);
        const float v2 = __uint_as_float(p2 << 16);
        const float v3 = __uint_as_float(p3 << 16);
        acc.x += v0 * __uint_as_float(g0.x << 16)         + v1 * __uint_as_float(g1.x << 16)
               + v2 * __uint_as_float(g2.x << 16)         + v3 * __uint_as_float(g3.x << 16);
        acc.y += v0 * __uint_as_float(g0.x & 0xFFFF0000u) + v1 * __uint_as_float(g1.x & 0xFFFF0000u)
               + v2 * __uint_as_float(g2.x & 0xFFFF0000u) + v3 * __uint_as_float(g3.x & 0xFFFF0000u);
        acc.z += v0 * __uint_as_float(g0.y << 16)         + v1 * __uint_as_float(g1.y << 16)
               + v2 * __uint_as_float(g2.y << 16)         + v3 * __uint_as_float(g3.y << 16);
        acc.w += v0 * __uint_as_float(g0.y & 0xFFFF0000u) + v1 * __uint_as_float(g1.y & 0xFFFF0000u)
               + v2 * __uint_as_float(g2.y & 0xFFFF0000u) + v3 * __uint_as_float(g3.y & 0xFFFF0000u);
    }
    for (; i < e; ++i) {
        const unsigned p0 = __builtin_nontemporal_load(&edges[i]);
        const u32x2 g0 = Wb[(size_t)(p0 >> 16) * 64 + lane];
        const float v0 = __uint_as_float(p0 << 16);
        acc.x += v0 * __uint_as_float(g0.x << 16);
        acc.y += v0 * __uint_as_float(g0.x & 0xFFFF0000u);
        acc.z += v0 * __uint_as_float(g0.y << 16);
        acc.w += v0 * __uint_as_float(g0.y & 0xFFFF0000u);
    }
    u32x2 o;
    o.x = f2bf(acc.x) | (f2bf(acc.y) << 16);
    o.y = f2bf(acc.z) | (f2bf(acc.w) << 16);
    xw[(size_t)wave * 64 + lane] = o;            // plain store: keep L2-warm
}

// ------- SpMM2: out(f32) = relu( sparse(adj) @ xw(bf16) ), 8-deep MLP -------

__global__ void spmm2(const int* __restrict__ offsets, const unsigned* __restrict__ edges,
                      const u32x2* __restrict__ xw, f32x4* __restrict__ out, int n) {
    const int wave = (int)((blockIdx.x * blockDim.x + threadIdx.x) >> 6);
    const int lane = (int)(threadIdx.x & 63);
    if (wave >= n) return;
    const int s = offsets[wave], e = offsets[wave + 1];

    float4 acc = make_float4(0.f, 0.f, 0.f, 0.f);
    int i = s;
    for (; i + 7 < e; i += 8) {
        unsigned p[8];
        #pragma unroll
        for (int k = 0; k < 8; ++k) p[k] = __builtin_nontemporal_load(&edges[i + k]);
        u32x2 g[8];
        #pragma unroll
        for (int k = 0; k < 8; ++k) g[k] = xw[(size_t)(p[k] >> 15) * 64 + lane];
        #pragma unroll
        for (int k = 0; k < 8; ++k) {
            const float v = __uint_as_float((p[k] & 0x7FFFu) << 16);
            acc.x += v * __uint_as_float(g[k].x << 16);
            acc.y += v * __uint_as_float(g[k].x & 0xFFFF0000u);
            acc.z += v * __uint_as_float(g[k].y << 16);
            acc.w += v * __uint_as_float(g[k].y & 0xFFFF0000u);
        }
    }
    for (; i < e; ++i) {
        const unsigned p0 = __builtin_nontemporal_load(&edges[i]);
        const u32x2 g0 = xw[(size_t)(p0 >> 15) * 64 + lane];
        const float v0 = __uint_as_float((p0 & 0x7FFFu) << 16);
        acc.x += v0 * __uint_as_float(g0.x << 16);
        acc.y += v0 * __uint_as_float(g0.x & 0xFFFF0000u);
        acc.z += v0 * __uint_as_float(g0.y << 16);
        acc.w += v0 * __uint_as_float(g0.y & 0xFFFF0000u);
    }
    f32x4 o;
    o.x = fmaxf(acc.x, 0.f); o.y = fmaxf(acc.y, 0.f);
    o.z = fmaxf(acc.z, 0.f); o.w = fmaxf(acc.w, 0.f);
    __builtin_nontemporal_store(o, &out[(size_t)wave * 64 + lane]);  // never re-read
}

// ---------------- fallback (atomic) path ----------------

__global__ void spmm_scatter(const int* __restrict__ rows, const int* __restrict__ cols,
                             const float* __restrict__ vals, const float* __restrict__ src,
                             float* __restrict__ dst, int nnz) {
    const int lane  = threadIdx.x & 63;
    const int wave  = (int)((blockIdx.x * blockDim.x + threadIdx.x) >> 6);
    const int nwave = (int)((gridDim.x * blockDim.x) >> 6);
    for (int e = wave; e < nnz; e += nwave) {
        const int r = rows[e];
        const int c = cols[e];
        const float v = vals[e];
        const float4 w = reinterpret_cast<const float4*>(src + (size_t)c * OUT_DIM)[lane];
        float* d = dst + (size_t)r * OUT_DIM + (size_t)lane * 4;
        atomicAdd(d + 0, v * w.x);
        atomicAdd(d + 1, v * w.y);
        atomicAdd(d + 2, v * w.z);
        atomicAdd(d + 3, v * w.w);
    }
}

__global__ void relu_inplace_f4(float4* __restrict__ p, int n4) {
    int i = blockIdx.x * blockDim.x + threadIdx.x;
    int stride = gridDim.x * blockDim.x;
    for (; i < n4; i += stride) {
        float4 v = p[i];
        v.x = fmaxf(v.x, 0.f); v.y = fmaxf(v.y, 0.f);
        v.z = fmaxf(v.z, 0.f); v.w = fmaxf(v.w, 0.f);
        p[i] = v;
    }
}

// -----------------------------------------------------------------------------

static inline size_t al16(size_t x) { return (x + 15) & ~(size_t)15; }

extern "C" void kernel_launch(void* const* d_in, const int* in_sizes, int n_in,
                              void* d_out, int out_size, void* d_ws, size_t ws_size,
                              hipStream_t stream) {
    const int*   x_rows   = (const int*)  d_in[0];
    const int*   x_cols   = (const int*)  d_in[1];
    const float* x_vals   = (const float*)d_in[2];
    const int*   adj_rows = (const int*)  d_in[3];
    const int*   adj_cols = (const int*)  d_in[4];
    const float* adj_vals = (const float*)d_in[5];
    const float* W        = (const float*)d_in[6];

    const int nnz_x   = in_sizes[0];
    const int nnz_adj = in_sizes[3];
    const int N       = out_size / OUT_DIM;          // 100000
    const int IN_DIM  = in_sizes[6] / OUT_DIM;       // 1024
    const int nbk     = (N + RPB - 1) / RPB;         // 391 buckets

    float* out = (float*)d_out;
    char*  ws  = (char*)d_ws;

    // ---- workspace layout ----
    const size_t xw_bytes  = al16((size_t)N * OUT_DIM * 2);        // bf16 xw
    const size_t wb_bytes  = al16((size_t)IN_DIM * OUT_DIM * 2);   // bf16 W
    const size_t off_bytes = al16((size_t)(N + 1) * 4);
    const size_t b_bytes   = al16((size_t)nbk * 4);
    const size_t qx_bytes  = al16((size_t)nnz_x * 8);
    const size_t qa_bytes  = al16((size_t)nnz_adj * 8);
    const size_t ex_bytes  = al16((size_t)nnz_x * 4);
    const size_t ea_bytes  = al16((size_t)nnz_adj * 4);
    const size_t need = xw_bytes + wb_bytes + 2 * off_bytes + 4 * b_bytes
                      + qx_bytes + qa_bytes + ex_bytes + ea_bytes;

    if (ws_size < need || nbk > MAXB || N > (1 << 17) || IN_DIM > (1 << 16)) {
        float* xwf = (float*)ws;
        (void)hipMemsetAsync(xwf, 0, (size_t)out_size * 4, stream);
        (void)hipMemsetAsync(out, 0, (size_t)out_size * 4, stream);
        spmm_scatter<<<8192, 256, 0, stream>>>(x_rows, x_cols, x_vals, W, xwf, nnz_x);
        spmm_scatter<<<8192, 256, 0, stream>>>(adj_rows, adj_cols, adj_vals, xwf, out, nnz_adj);
        relu_inplace_f4<<<2048, 256, 0, stream>>>((float4*)out, out_size / 4);
        return;
    }

    char* p = ws;
    u32x2*    xw      = (u32x2*)p;    p += xw_bytes;
    u32x2*    Wb      = (u32x2*)p;    p += wb_bytes;
    int*      off_x   = (int*)p;      p += off_bytes;
    int*      off_a   = (int*)p;      p += off_bytes;
    int*      bcx     = (int*)p;      p += b_bytes;
    int*      bca     = (int*)p;      p += b_bytes;   // contiguous with bcx
    int*      gcx     = (int*)p;      p += b_bytes;
    int*      gca     = (int*)p;      p += b_bytes;
    u32x2*    qx      = (u32x2*)p;    p += qx_bytes;
    u32x2*    qa      = (u32x2*)p;    p += qa_bytes;
    unsigned* edges_x = (unsigned*)p; p += ex_bytes;
    unsigned* edges_a = (unsigned*)p; p += ea_bytes;

    const int spmm_blocks = (N + 3) / 4;                   // 4 waves / block
    const int n_wb        = IN_DIM * (OUT_DIM / 4);        // u32x2 entries in Wb
    const int scat_x_blk  = (nnz_x + CHUNK - 1) / CHUNK;
    const int scat_a_blk  = (nnz_adj + CHUNK - 1) / CHUNK;

    // ---- bucket sort (both matrices) ----
    (void)hipMemsetAsync(bcx, 0, 2 * b_bytes, stream);     // bcx + bca
    bhist2<<<2048, 256, 0, stream>>>(x_rows, nnz_x, adj_rows, nnz_adj,
                                     bcx, bca, W, Wb, n_wb, nbk);
    bscan2<<<2, MAXB, 0, stream>>>(bcx, bca, gcx, gca, nbk);
    bscatter<<<scat_x_blk, 256, 0, stream>>>(x_rows, x_cols, x_vals, gcx, qx, nnz_x, nbk);
    bscatter<<<scat_a_blk, 256, 0, stream>>>(adj_rows, adj_cols, adj_vals, gca, qa, nnz_adj, nbk);
    bfinal<false><<<nbk, RPB, 0, stream>>>(qx, bcx, edges_x, off_x, N, nnz_x, nbk);
    bfinal<true><<<nbk, RPB, 0, stream>>>(qa, bca, edges_a, off_a, N, nnz_adj, nbk);

    // ---- SpMMs ----
    spmm1<<<spmm_blocks, 256, 0, stream>>>(off_x, edges_x, Wb, xw, N);
    spmm2<<<spmm_blocks, 256, 0, stream>>>(off_a, edges_a, xw, (f32x4*)out, N);
}

// Round 13
// 561.255 us; speedup vs baseline: 1.9052x; 1.0672x over previous
//
#include <hip/hip_runtime.h>

// GCN sparse conv: out = relu( sparse(adj) @ ( sparse(x) @ W ) )
// Bucket-granular counting sort (256 rows/bucket):
//   bhist2:    LDS-aggregated bucket histogram for both matrices (+W->bf16)
//   bscan2:    exclusive scan of bucket counts -> bases + global cursors
//   bscatter2: 4096-edge chunks (grid split x|adj); LDS hist -> ONE global
//              fetch-add per (block,bucket); LDS re-rank; coalesced flush.
//   bfinal2:   one block per bucket (grid split x|adj): per-row LDS
//              count/scan/re-rank -> CSR offsets + packed 4B edges.
// SpMM (half-wave paired): lanes 0-31 gather edge i's source row in 16B
// slices, lanes 32-63 edge i+1; lane owns an 8-col slice; __shfl_xor(32)
// merges halves. 8-pair unroll = 16 edges/iter = 128B in flight per lane.
// Edge words 4B: x = col<<16 | bf16(val); adj = col<<15 | bf15(val>=0).
// xw bf16, plain stores (L2-warm for spmm2); NT stores only for final out.

constexpr int OUT_DIM = 256;
constexpr int RPB     = 256;     // rows per bucket
constexpr int RPB_SH  = 8;
constexpr int MAXB    = 1024;    // max buckets (N <= 262144)
constexpr int CHUNK   = 4096;    // edges per bscatter block

typedef float        f32x4 __attribute__((ext_vector_type(4)));
typedef unsigned int u32x2 __attribute__((ext_vector_type(2)));
typedef unsigned int u32x4 __attribute__((ext_vector_type(4)));

static __device__ __forceinline__ unsigned f2bf(float f) {
    unsigned u = __float_as_uint(f);
    return (u + 0x7FFFu + ((u >> 16) & 1u)) >> 16;   // round-nearest-even
}
static __device__ __forceinline__ float blo(unsigned w) { return __uint_as_float(w << 16); }
static __device__ __forceinline__ float bhi(unsigned w) { return __uint_as_float(w & 0xFFFF0000u); }

// ------- bucket histogram (both matrices) + W->bf16 -------

__global__ void bhist2(const int* __restrict__ xr, int nx,
                       const int* __restrict__ ar, int na,
                       int* __restrict__ bcx, int* __restrict__ bca,
                       const float* __restrict__ W, u32x2* __restrict__ Wb,
                       int n_wb, int nbk) {
    __shared__ int hx[MAXB], ha[MAXB];
    const int t = (int)threadIdx.x;
    for (int j = t; j < nbk; j += 256) { hx[j] = 0; ha[j] = 0; }
    __syncthreads();
    int i = (int)(blockIdx.x * blockDim.x + threadIdx.x);
    const int stride = (int)(gridDim.x * blockDim.x);
    const int tot = nx + na + n_wb;
    for (; i < tot; i += stride) {
        if (i < nx) {
            atomicAdd(&hx[__builtin_nontemporal_load(&xr[i]) >> RPB_SH], 1);
        } else if (i < nx + na) {
            atomicAdd(&ha[__builtin_nontemporal_load(&ar[i - nx]) >> RPB_SH], 1);
        } else {
            const int j = i - nx - na;
            const float4 w = reinterpret_cast<const float4*>(W)[j];
            u32x2 o;
            o.x = f2bf(w.x) | (f2bf(w.y) << 16);
            o.y = f2bf(w.z) | (f2bf(w.w) << 16);
            Wb[j] = o;
        }
    }
    __syncthreads();
    for (int j = t; j < nbk; j += 256) {
        if (hx[j]) atomicAdd(&bcx[j], hx[j]);
        if (ha[j]) atomicAdd(&bca[j], ha[j]);
    }
}

// ------- exclusive scan of bucket counts (in place) + cursor init -------

__global__ void bscan2(int* __restrict__ bx, int* __restrict__ ba,
                       int* __restrict__ gx, int* __restrict__ ga, int nbk) {
    __shared__ int sh[MAXB];
    int* bs = (blockIdx.x == 0) ? bx : ba;
    int* gc = (blockIdx.x == 0) ? gx : ga;
    const int t = (int)threadIdx.x;
    const int v = (t < nbk) ? bs[t] : 0;
    sh[t] = v;
    __syncthreads();
    for (int off = 1; off < MAXB; off <<= 1) {
        int cur = sh[t];
        int a = (t >= off) ? sh[t - off] : 0;
        __syncthreads();
        sh[t] = cur + a;
        __syncthreads();
    }
    if (t < nbk) {
        const int e = sh[t] - v;   // exclusive
        bs[t] = e;
        gc[t] = e;
    }
}

// ------- aggregated bucket scatter (grid split x | adj) -------
// q entry: .x = rowInBucket(8b)<<17 | col(17b);  .y = f32 val bits.

static __device__ __forceinline__ void bscatter_body(
        const int* __restrict__ rows, const int* __restrict__ cols,
        const float* __restrict__ vals, int* __restrict__ gcur,
        u32x2* __restrict__ q, int nnz, int nbk, int blk) {
    __shared__ u32x2 stage[CHUNK];
    __shared__ int   saddr[CHUNK];
    __shared__ int   lcnt[MAXB], lstart[MAXB], gstart[MAXB];
    __shared__ int   ssum[256];
    const int t    = (int)threadIdx.x;
    const int base = blk * CHUNK;
    const int cnt  = min(CHUNK, nnz - base);

    for (int j = t; j < nbk; j += 256) lcnt[j] = 0;
    __syncthreads();

    unsigned ex[16], ey[16];
    int my[16], bk[16];
    #pragma unroll
    for (int k = 0; k < 16; ++k) {
        const int i = base + k * 256 + t;
        bk[k] = -1;
        if (i < nnz) {
            const int   r = __builtin_nontemporal_load(&rows[i]);
            const int   c = __builtin_nontemporal_load(&cols[i]);
            const float v = __builtin_nontemporal_load(&vals[i]);
            bk[k] = r >> RPB_SH;
            ex[k] = ((unsigned)(r & (RPB - 1)) << 17) | (unsigned)c;
            ey[k] = __float_as_uint(v);
            my[k] = atomicAdd(&lcnt[bk[k]], 1);
        }
    }
    __syncthreads();

    {   // local exclusive scan of lcnt -> lstart
        const int idx = t * 4;
        const int c0 = (idx + 0 < nbk) ? lcnt[idx + 0] : 0;
        const int c1 = (idx + 1 < nbk) ? lcnt[idx + 1] : 0;
        const int c2 = (idx + 2 < nbk) ? lcnt[idx + 2] : 0;
        const int c3 = (idx + 3 < nbk) ? lcnt[idx + 3] : 0;
        const int tsum = c0 + c1 + c2 + c3;
        ssum[t] = tsum;
        __syncthreads();
        for (int off = 1; off < 256; off <<= 1) {
            int cur = ssum[t];
            int a = (t >= off) ? ssum[t - off] : 0;
            __syncthreads();
            ssum[t] = cur + a;
            __syncthreads();
        }
        const int b0 = ssum[t] - tsum;
        lstart[idx + 0] = b0;
        lstart[idx + 1] = b0 + c0;
        lstart[idx + 2] = b0 + c0 + c1;
        lstart[idx + 3] = b0 + c0 + c1 + c2;
    }
    for (int j = t; j < nbk; j += 256) {
        const int c = lcnt[j];
        gstart[j] = c ? atomicAdd(&gcur[j], c) : 0;
    }
    __syncthreads();

    #pragma unroll
    for (int k = 0; k < 16; ++k) {
        if (bk[k] >= 0) {
            const int slot = lstart[bk[k]] + my[k];
            u32x2 e; e.x = ex[k]; e.y = ey[k];
            stage[slot] = e;
            saddr[slot] = gstart[bk[k]] + my[k];
        }
    }
    __syncthreads();
    for (int s = t; s < cnt; s += 256)
        q[saddr[s]] = stage[s];
}

__global__ void bscatter2(const int* __restrict__ xr, const int* __restrict__ xc,
                          const float* __restrict__ xv, int* __restrict__ gcx,
                          u32x2* __restrict__ qx, int nx, int xblk,
                          const int* __restrict__ ar, const int* __restrict__ ac,
                          const float* __restrict__ av, int* __restrict__ gca,
                          u32x2* __restrict__ qa, int na, int nbk) {
    if ((int)blockIdx.x < xblk)
        bscatter_body(xr, xc, xv, gcx, qx, nx, nbk, (int)blockIdx.x);
    else
        bscatter_body(ar, ac, av, gca, qa, na, nbk, (int)blockIdx.x - xblk);
}

// ------- per-bucket finalize (grid split x | adj) -------

static __device__ __forceinline__ void bfinal_body(
        const u32x2* __restrict__ q, const int* __restrict__ bbase,
        unsigned* __restrict__ edges, int* __restrict__ offsets,
        int N, int nnz, int nbk, int b, bool adj) {
    __shared__ int cnt[RPB], cur[RPB];
    const int t  = (int)threadIdx.x;
    const int gb = bbase[b];
    const int ge = (b + 1 < nbk) ? bbase[b + 1] : nnz;

    cnt[t] = 0;
    __syncthreads();
    for (int i = gb + t; i < ge; i += 256)
        atomicAdd(&cnt[q[i].x >> 17], 1);
    __syncthreads();

    const int c = cnt[t];
    cur[t] = c;
    __syncthreads();
    for (int off = 1; off < 256; off <<= 1) {
        int v = cur[t];
        int a = (t >= off) ? cur[t - off] : 0;
        __syncthreads();
        cur[t] = v + a;
        __syncthreads();
    }
    const int excl = cur[t] - c;
    const int r = b * RPB + t;
    if (r < N) offsets[r] = gb + excl;
    if (b == nbk - 1 && t == 0) offsets[N] = nnz;
    __syncthreads();
    cur[t] = gb + excl;
    __syncthreads();

    for (int i = gb + t; i < ge; i += 256) {
        const u32x2 e = q[i];
        const int rank = atomicAdd(&cur[e.x >> 17], 1);
        const unsigned col = e.x & 0x1FFFFu;
        const float v = __uint_as_float(e.y);
        edges[rank] = adj ? ((col << 15) | (f2bf(v) & 0x7FFFu))
                          : ((col << 16) | f2bf(v));
    }
}

__global__ void bfinal2(const u32x2* __restrict__ qx, const int* __restrict__ bcx,
                        unsigned* __restrict__ ex, int* __restrict__ ox, int nx,
                        const u32x2* __restrict__ qa, const int* __restrict__ bca,
                        unsigned* __restrict__ ea, int* __restrict__ oa, int na,
                        int N, int nbk) {
    if ((int)blockIdx.x < nbk)
        bfinal_body(qx, bcx, ex, ox, N, nx, nbk, (int)blockIdx.x, false);
    else
        bfinal_body(qa, bca, ea, oa, N, na, nbk, (int)blockIdx.x - nbk, true);
}

// ------- SpMM1 (paired): xw(bf16) = sparse(x) @ Wb(bf16) -------
// Half-wave pairing: lanes<32 gather even edges, lanes>=32 odd edges, 16B
// slices; lane owns cols [8sl, 8sl+8); xor-32 merge; 8B coalesced bf16 write.

__global__ void spmm1(const int* __restrict__ offsets, const unsigned* __restrict__ edges,
                      const u32x4* __restrict__ Wb4, u32x2* __restrict__ xw, int n) {
    const int wave = (int)((blockIdx.x * blockDim.x + threadIdx.x) >> 6);
    const int lane = (int)(threadIdx.x & 63);
    if (wave >= n) return;
    const int half = lane >> 5, sl = lane & 31;
    const int s = offsets[wave], e = offsets[wave + 1];

    float a0 = 0.f, a1 = 0.f, a2 = 0.f, a3 = 0.f, a4 = 0.f, a5 = 0.f, a6 = 0.f, a7 = 0.f;
    int i = s;
    for (; i + 15 < e; i += 16) {
        unsigned p[8];
        #pragma unroll
        for (int j = 0; j < 8; ++j) p[j] = __builtin_nontemporal_load(&edges[i + 2 * j + half]);
        u32x4 g[8];
        #pragma unroll
        for (int j = 0; j < 8; ++j) g[j] = Wb4[(size_t)(p[j] >> 16) * 32 + sl];
        #pragma unroll
        for (int j = 0; j < 8; ++j) {
            const float v = blo(p[j]);
            a0 += v * blo(g[j].x); a1 += v * bhi(g[j].x);
            a2 += v * blo(g[j].y); a3 += v * bhi(g[j].y);
            a4 += v * blo(g[j].z); a5 += v * bhi(g[j].z);
            a6 += v * blo(g[j].w); a7 += v * bhi(g[j].w);
        }
    }
    for (; i < e; i += 2) {
        const int idx = i + half;
        const bool ok = idx < e;
        const unsigned p = ok ? __builtin_nontemporal_load(&edges[idx]) : 0u;
        const u32x4 g = Wb4[(size_t)(p >> 16) * 32 + sl];
        const float v = ok ? blo(p) : 0.f;
        a0 += v * blo(g.x); a1 += v * bhi(g.x);
        a2 += v * blo(g.y); a3 += v * bhi(g.y);
        a4 += v * blo(g.z); a5 += v * bhi(g.z);
        a6 += v * blo(g.w); a7 += v * bhi(g.w);
    }
    a0 += __shfl_xor(a0, 32); a1 += __shfl_xor(a1, 32);
    a2 += __shfl_xor(a2, 32); a3 += __shfl_xor(a3, 32);
    a4 += __shfl_xor(a4, 32); a5 += __shfl_xor(a5, 32);
    a6 += __shfl_xor(a6, 32); a7 += __shfl_xor(a7, 32);
    u32x2 o;
    if (half == 0) { o.x = f2bf(a0) | (f2bf(a1) << 16); o.y = f2bf(a2) | (f2bf(a3) << 16); }
    else           { o.x = f2bf(a4) | (f2bf(a5) << 16); o.y = f2bf(a6) | (f2bf(a7) << 16); }
    xw[(size_t)wave * 64 + 2 * sl + half] = o;     // plain store: keep L2-warm
}

// ------- SpMM2 (paired): out(f32) = relu( sparse(adj) @ xw(bf16) ) -------

__global__ void spmm2(const int* __restrict__ offsets, const unsigned* __restrict__ edges,
                      const u32x4* __restrict__ xw4, f32x4* __restrict__ out, int n) {
    const int wave = (int)((blockIdx.x * blockDim.x + threadIdx.x) >> 6);
    const int lane = (int)(threadIdx.x & 63);
    if (wave >= n) return;
    const int half = lane >> 5, sl = lane & 31;
    const int s = offsets[wave], e = offsets[wave + 1];

    float a0 = 0.f, a1 = 0.f, a2 = 0.f, a3 = 0.f, a4 = 0.f, a5 = 0.f, a6 = 0.f, a7 = 0.f;
    int i = s;
    for (; i + 15 < e; i += 16) {
        unsigned p[8];
        #pragma unroll
        for (int j = 0; j < 8; ++j) p[j] = __builtin_nontemporal_load(&edges[i + 2 * j + half]);
        u32x4 g[8];
        #pragma unroll
        for (int j = 0; j < 8; ++j) g[j] = xw4[(size_t)(p[j] >> 15) * 32 + sl];
        #pragma unroll
        for (int j = 0; j < 8; ++j) {
            const float v = __uint_as_float((p[j] & 0x7FFFu) << 16);
            a0 += v * blo(g[j].x); a1 += v * bhi(g[j].x);
            a2 += v * blo(g[j].y); a3 += v * bhi(g[j].y);
            a4 += v * blo(g[j].z); a5 += v * bhi(g[j].z);
            a6 += v * blo(g[j].w); a7 += v * bhi(g[j].w);
        }
    }
    for (; i < e; i += 2) {
        const int idx = i + half;
        const bool ok = idx < e;
        const unsigned p = ok ? __builtin_nontemporal_load(&edges[idx]) : 0u;
        const u32x4 g = xw4[(size_t)(p >> 15) * 32 + sl];
        const float v = ok ? __uint_as_float((p & 0x7FFFu) << 16) : 0.f;
        a0 += v * blo(g.x); a1 += v * bhi(g.x);
        a2 += v * blo(g.y); a3 += v * bhi(g.y);
        a4 += v * blo(g.z); a5 += v * bhi(g.z);
        a6 += v * blo(g.w); a7 += v * bhi(g.w);
    }
    a0 += __shfl_xor(a0, 32); a1 += __shfl_xor(a1, 32);
    a2 += __shfl_xor(a2, 32); a3 += __shfl_xor(a3, 32);
    a4 += __shfl_xor(a4, 32); a5 += __shfl_xor(a5, 32);
    a6 += __shfl_xor(a6, 32); a7 += __shfl_xor(a7, 32);
    f32x4 o;
    if (half == 0) { o.x = fmaxf(a0, 0.f); o.y = fmaxf(a1, 0.f);
                     o.z = fmaxf(a2, 0.f); o.w = fmaxf(a3, 0.f); }
    else           { o.x = fmaxf(a4, 0.f); o.y = fmaxf(a5, 0.f);
                     o.z = fmaxf(a6, 0.f); o.w = fmaxf(a7, 0.f); }
    __builtin_nontemporal_store(o, &out[(size_t)wave * 64 + 2 * sl + half]);
}

// ---------------- fallback (atomic) path ----------------

__global__ void spmm_scatter(const int* __restrict__ rows, const int* __restrict__ cols,
                             const float* __restrict__ vals, const float* __restrict__ src,
                             float* __restrict__ dst, int nnz) {
    const int lane  = threadIdx.x & 63;
    const int wave  = (int)((blockIdx.x * blockDim.x + threadIdx.x) >> 6);
    const int nwave = (int)((gridDim.x * blockDim.x) >> 6);
    for (int e = wave; e < nnz; e += nwave) {
        const int r = rows[e];
        const int c = cols[e];
        const float v = vals[e];
        const float4 w = reinterpret_cast<const float4*>(src + (size_t)c * OUT_DIM)[lane];
        float* d = dst + (size_t)r * OUT_DIM + (size_t)lane * 4;
        atomicAdd(d + 0, v * w.x);
        atomicAdd(d + 1, v * w.y);
        atomicAdd(d + 2, v * w.z);
        atomicAdd(d + 3, v * w.w);
    }
}

__global__ void relu_inplace_f4(float4* __restrict__ p, int n4) {
    int i = blockIdx.x * blockDim.x + threadIdx.x;
    int stride = gridDim.x * blockDim.x;
    for (; i < n4; i += stride) {
        float4 v = p[i];
        v.x = fmaxf(v.x, 0.f); v.y = fmaxf(v.y, 0.f);
        v.z = fmaxf(v.z, 0.f); v.w = fmaxf(v.w, 0.f);
        p[i] = v;
    }
}

// -----------------------------------------------------------------------------

static inline size_t al16(size_t x) { return (x + 15) & ~(size_t)15; }

extern "C" void kernel_launch(void* const* d_in, const int* in_sizes, int n_in,
                              void* d_out, int out_size, void* d_ws, size_t ws_size,
                              hipStream_t stream) {
    const int*   x_rows   = (const int*)  d_in[0];
    const int*   x_cols   = (const int*)  d_in[1];
    const float* x_vals   = (const float*)d_in[2];
    const int*   adj_rows = (const int*)  d_in[3];
    const int*   adj_cols = (const int*)  d_in[4];
    const float* adj_vals = (const float*)d_in[5];
    const float* W        = (const float*)d_in[6];

    const int nnz_x   = in_sizes[0];
    const int nnz_adj = in_sizes[3];
    const int N       = out_size / OUT_DIM;          // 100000
    const int IN_DIM  = in_sizes[6] / OUT_DIM;       // 1024
    const int nbk     = (N + RPB - 1) / RPB;         // 391 buckets

    float* out = (float*)d_out;
    char*  ws  = (char*)d_ws;

    // ---- workspace layout ----
    const size_t xw_bytes  = al16((size_t)N * OUT_DIM * 2);        // bf16 xw
    const size_t wb_bytes  = al16((size_t)IN_DIM * OUT_DIM * 2);   // bf16 W
    const size_t off_bytes = al16((size_t)(N + 1) * 4);
    const size_t b_bytes   = al16((size_t)nbk * 4);
    const size_t qx_bytes  = al16((size_t)nnz_x * 8);
    const size_t qa_bytes  = al16((size_t)nnz_adj * 8);
    const size_t ex_bytes  = al16((size_t)nnz_x * 4);
    const size_t ea_bytes  = al16((size_t)nnz_adj * 4);
    const size_t need = xw_bytes + wb_bytes + 2 * off_bytes + 4 * b_bytes
                      + qx_bytes + qa_bytes + ex_bytes + ea_bytes;

    if (ws_size < need || nbk > MAXB || N > (1 << 17) || IN_DIM > (1 << 16)) {
        float* xwf = (float*)ws;
        (void)hipMemsetAsync(xwf, 0, (size_t)out_size * 4, stream);
        (void)hipMemsetAsync(out, 0, (size_t)out_size * 4, stream);
        spmm_scatter<<<8192, 256, 0, stream>>>(x_rows, x_cols, x_vals, W, xwf, nnz_x);
        spmm_scatter<<<8192, 256, 0, stream>>>(adj_rows, adj_cols, adj_vals, xwf, out, nnz_adj);
        relu_inplace_f4<<<2048, 256, 0, stream>>>((float4*)out, out_size / 4);
        return;
    }

    char* p = ws;
    u32x2*    xw      = (u32x2*)p;    p += xw_bytes;
    u32x2*    Wb      = (u32x2*)p;    p += wb_bytes;
    int*      off_x   = (int*)p;      p += off_bytes;
    int*      off_a   = (int*)p;      p += off_bytes;
    int*      bcx     = (int*)p;      p += b_bytes;
    int*      bca     = (int*)p;      p += b_bytes;   // contiguous with bcx
    int*      gcx     = (int*)p;      p += b_bytes;
    int*      gca     = (int*)p;      p += b_bytes;
    u32x2*    qx      = (u32x2*)p;    p += qx_bytes;
    u32x2*    qa      = (u32x2*)p;    p += qa_bytes;
    unsigned* edges_x = (unsigned*)p; p += ex_bytes;
    unsigned* edges_a = (unsigned*)p; p += ea_bytes;

    const int spmm_blocks = (N + 3) / 4;                   // 4 waves / block
    const int n_wb        = IN_DIM * (OUT_DIM / 4);        // u32x2 entries in Wb
    const int scat_x_blk  = (nnz_x + CHUNK - 1) / CHUNK;
    const int scat_a_blk  = (nnz_adj + CHUNK - 1) / CHUNK;

    // ---- bucket sort (both matrices) ----
    (void)hipMemsetAsync(bcx, 0, 2 * b_bytes, stream);     // bcx + bca
    bhist2<<<2048, 256, 0, stream>>>(x_rows, nnz_x, adj_rows, nnz_adj,
                                     bcx, bca, W, Wb, n_wb, nbk);
    bscan2<<<2, MAXB, 0, stream>>>(bcx, bca, gcx, gca, nbk);
    bscatter2<<<scat_x_blk + scat_a_blk, 256, 0, stream>>>(
        x_rows, x_cols, x_vals, gcx, qx, nnz_x, scat_x_blk,
        adj_rows, adj_cols, adj_vals, gca, qa, nnz_adj, nbk);
    bfinal2<<<2 * nbk, RPB, 0, stream>>>(qx, bcx, edges_x, off_x, nnz_x,
                                         qa, bca, edges_a, off_a, nnz_adj, N, nbk);

    // ---- SpMMs (half-wave paired) ----
    spmm1<<<spmm_blocks, 256, 0, stream>>>(off_x, edges_x, (const u32x4*)Wb, xw, N);
    spmm2<<<spmm_blocks, 256, 0, stream>>>(off_a, edges_a, (const u32x4*)xw, (f32x4*)out, N);
}